// Round 9
// baseline (609.340 us; speedup 1.0000x reference)
//
#include <hip/hip_runtime.h>
#include <cstdint>
#include <cstddef>

// ============================================================================
// CHMLearner forward. R9: chm6d v5 (software-pipelined double-buffered plane
// staging — write pr+1 before computing pr; contiguous aligned weight pack
// K6P for batched s_loads). Rest kept from R8.
// ============================================================================

#define DEVFN __device__ __forceinline__

typedef __attribute__((ext_vector_type(8))) short short8v;
typedef __attribute__((ext_vector_type(4))) float f32x4;
typedef unsigned int u32;

DEVFN void gl_lds16(const void* g, void* l){
  __builtin_amdgcn_global_load_lds(
      (const __attribute__((address_space(1))) u32*)g,
      (__attribute__((address_space(3))) u32*)l, 16, 0, 0);
}

// workspace layout (float units). Total ~61 MB
constexpr size_t OFF_WB    = 0;           // bf16 packed weights, 3*2,359,296 bf16
constexpr size_t OFF_P8    = 3538944;     // bf16 padded ch-last features
constexpr size_t OFF_P16   = 3948544;
constexpr size_t OFF_P32   = 5275648;
constexpr size_t OFF_SF8   = 10010624;    // conv outputs f32 [b][256][S*S]
constexpr size_t OFF_TF8   = 10076160;
constexpr size_t OFF_SF16  = 10141696;
constexpr size_t OFF_TF16  = 10403840;
constexpr size_t OFF_SF32  = 10665984;
constexpr size_t OFF_TF32  = 11714560;
constexpr size_t OFF_INVS  = 12763136;
constexpr size_t OFF_INVT  = 12768512;
constexpr size_t OFF_SMAX  = 12773888;
constexpr size_t OFF_TMAX  = 12777984;
constexpr size_t OFF_CORR6 = 12782080;    // [4][9][16^4]
constexpr size_t OFF_CMAXP = OFF_CORR6 + 2359296 + 128;   // 32768 colmax partials
constexpr size_t OFF_K6P   = OFF_CMAXP + 32768;           // 54000 packed 6d weights
constexpr size_t WS_FLOATS = OFF_K6P + 54016;

// aliases into dead regions (all of [0, 10,010,624) is dead post-corr):
__device__ constexpr size_t PAIR_OFF[9] = {   // raw per-pair corr [4][ss^2][ts^2]
  OFF_WB + 0,       OFF_WB + 16384,   OFF_WB + 81920,
  OFF_WB + 344064,  OFF_WB + 409600,  OFF_WB + 671744,
  OFF_WB + 1720320, OFF_WB + 1982464, OFF_WB + 3031040 };
constexpr size_t OFF_PART  = 0;            // [4g][4b][9so][16^4] = 9,437,184 floats
constexpr size_t OFF_MAXED = 9437184;      // [4][16^4]
constexpr size_t OFF_INT32 = 262144;       // [4][32^4] (PART dead by interp32 time)

__device__ constexpr int SSARR[3] = {8, 16, 32};
__device__ constexpr int PAIR_START[9] = {0,4,20,84,100,164,420,484,740}; // 1764

DEVFN unsigned short f2bf(float f){
  unsigned int u = __float_as_uint(f);
  return (unsigned short)((u + 0x7fffu + ((u >> 16) & 1u)) >> 16);
}

// ---------------------------------------------------------------------------
// 1) pack conv weights into MFMA A-fragment order (bf16)
__global__ void k_wpack(const float* __restrict__ w0, const float* __restrict__ w1,
                        const float* __restrict__ w2, float* __restrict__ wsf){
  int gid = blockIdx.x*256 + threadIdx.x;        // 884,736 exact
  int scale = gid / 294912, r = gid % 294912;
  int tap = r >> 15, kc = (r>>10)&31, nc = (r>>6)&15, l = r&63;
  const float* w = (scale==0) ? w0 : (scale==1 ? w1 : w2);
  int co = nc*16 + (l&15);
  int ci0 = kc*32 + ((l>>4)&3)*8;
  unsigned short* o = (unsigned short*)(wsf + OFF_WB) + (size_t)gid*8;
  #pragma unroll
  for (int i=0;i<8;i++)
    o[i] = f2bf(w[((size_t)co*1024 + ci0 + i)*9 + tap]);
}

// 1b) pack chm6d weights: K6P[(a*5+c)][pr][d][48] ; slot s=ki*3+kj, j=s*5+e
__global__ void k_k6p(const float* __restrict__ k6, float* __restrict__ ws){
  int gid = blockIdx.x*256 + threadIdx.x;        // 54,000
  if (gid >= 54000) return;
  int ac = gid / 2160, r = gid % 2160;
  int pr = r / 240; int r2 = r % 240;
  int d = r2 / 48, j = r2 % 48;
  float v = 0.f;
  if (j < 45){
    int s = j/5, e = j%5;
    int a = ac/5, c = ac%5;
    v = k6[(((s*5 + a)*5 + c)*5 + d)*5 + e];
  }
  (void)pr;
  ws[OFF_K6P + gid] = v;
}

// ---------------------------------------------------------------------------
// 2) inpack: stage 16 channels' 16x16 planes in LDS; emit all 3 scales
__global__ __launch_bounds__(256) void k_inpack(const float* __restrict__ src,
                                                const float* __restrict__ trg,
                                                float* __restrict__ wsf){
  int bt = blockIdx.x >> 6, cg = blockIdx.x & 63;
  int chbase = cg*16;
  int t = threadIdx.x;
  __shared__ float sIn[16][257];
  const float* gin = ((bt>=4)? trg : src) + ((size_t)(bt&3)*1024 + chbase)*256;
  #pragma unroll
  for (int i=0;i<16;i++){
    int idx = t + i*256; int ch = idx>>8, pos = idx&255;
    sIn[ch][pos] = gin[(size_t)ch*256 + pos];
  }
  __syncthreads();
  int ch = t & 15, pw = t >> 4;
  #pragma unroll 1
  for (int s=0; s<3; s++){
    int S = SSARR[s], Sp = S+2, Sp2 = Sp*Sp;
    size_t poff = (s==0)?OFF_P8 : (s==1)?OFF_P16 : OFF_P32;
    unsigned short* o = (unsigned short*)(wsf + poff) + (size_t)bt*Sp2*1024 + chbase + ch;
    float rs = 15.f/(float)(S-1);
    for (int i = pw; i < Sp2; i += 16){
      int py = i / Sp, px = i % Sp;
      float v = 0.f;
      if (py>0 && py<Sp-1 && px>0 && px<Sp-1){
        float cy = (float)(py-1)*rs, cx = (float)(px-1)*rs;
        int y0 = (int)cy; if (y0>15) y0=15; int y1 = (y0+1<16)?y0+1:15; float fy = cy-(float)y0;
        int x0 = (int)cx; if (x0>15) x0=15; int x1 = (x0+1<16)?x0+1:15; float fx = cx-(float)x0;
        v = (1.f-fy)*((1.f-fx)*sIn[ch][y0*16+x0] + fx*sIn[ch][y0*16+x1])
          +       fy*((1.f-fx)*sIn[ch][y1*16+x0] + fx*sIn[ch][y1*16+x1]);
      }
      o[(size_t)i*1024] = f2bf(v);
    }
  }
}

// ---------------------------------------------------------------------------
// 3) conv3x3 as bf16 MFMA GEMM with LDS double-buffer + global_load_lds.
__global__ __launch_bounds__(256) void k_conv_mfma(float* __restrict__ wsf){
  int bx = (blockIdx.x & 7)*42 + (blockIdx.x >> 3);   // bijective, 336 blocks
  int scale, bt, cot, post, S, lgS;
  if (bx < 256)      { scale=2; S=32; lgS=5; bt=bx>>5; cot=(bx>>4)&1; post=bx&15; }
  else if (bx < 320) { int r=bx-256; scale=1; S=16; lgS=4; bt=r>>3; cot=(r>>2)&1; post=r&3; }
  else               { int r=bx-320; scale=0; S=8;  lgS=3; bt=r>>1; cot=r&1; post=0; }
  const int Sp = S+2, N = S*S;
  const unsigned short* WbS = (const unsigned short*)(wsf + OFF_WB) + (size_t)scale*2359296;
  size_t poff = scale==0?OFF_P8: scale==1?OFF_P16:OFF_P32;
  const unsigned short* Pb = (const unsigned short*)(wsf + poff) + (size_t)bt*Sp*Sp*1024;
  size_t obase = (scale==2) ? (bt>=4?OFF_TF32:OFF_SF32)
               : (scale==1) ? (bt>=4?OFF_TF16:OFF_SF16)
                            : (bt>=4?OFF_TF8 :OFF_SF8);
  float* outp = wsf + obase + (size_t)(bt&3)*256*N;

  const int t = threadIdx.x, l = t&63, w = t>>6, wm = w&1, wn = w>>1;
  const int nc_base = cot*8;
  const int pos0 = post*64;

  __shared__ __align__(16) unsigned short Ab[2][8192];   // 32 KB
  __shared__ __align__(16) unsigned short Bb[2][4096];   // 16 KB

  f32x4 acc[4][2];
  #pragma unroll
  for (int i=0;i<4;i++)
    #pragma unroll
    for (int j=0;j<2;j++) acc[i][j] = (f32x4){0.f,0.f,0.f,0.f};

  auto STAGE = [&](int buf, int it){
    int tap = it>>4, kq = it&15;
    int dy = tap/3, dx = tap - dy*3;
    #pragma unroll
    for (int j=0;j<4;++j){
      int c = w + j*4;
      int kc = c>>3, nc = c&7;
      const unsigned short* src =
        WbS + ((((size_t)tap*32 + kq*2 + kc)*16 + nc_base + nc)*64 + l)*8;
      gl_lds16(src, &Ab[buf][c*512]);
    }
    #pragma unroll
    for (int j=0;j<2;++j){
      int c = w + j*4;
      int kc = c>>2, np = c&3;
      int pos = pos0 + np*16 + (l&15);
      int y = pos>>lgS, x = pos&(S-1);
      int row = (y+dy)*Sp + (x+dx);
      int ci = kq*64 + kc*32 + ((l>>4)<<3);
      gl_lds16(Pb + (size_t)row*1024 + ci, &Bb[buf][c*512]);
    }
  };

  STAGE(0, 0);
  __syncthreads();
  int buf = 0;
  #pragma unroll 1
  for (int it=0; it<144; ++it){
    if (it+1 < 144) STAGE(buf^1, it+1);
    #pragma unroll
    for (int kc=0; kc<2; ++kc){
      short8v a0 = *(const short8v*)&Ab[buf][((kc*8 + wm*4 + 0)*64 + l)*8];
      short8v a1 = *(const short8v*)&Ab[buf][((kc*8 + wm*4 + 1)*64 + l)*8];
      short8v a2 = *(const short8v*)&Ab[buf][((kc*8 + wm*4 + 2)*64 + l)*8];
      short8v a3 = *(const short8v*)&Ab[buf][((kc*8 + wm*4 + 3)*64 + l)*8];
      short8v b0 = *(const short8v*)&Bb[buf][((kc*4 + wn*2 + 0)*64 + l)*8];
      short8v b1 = *(const short8v*)&Bb[buf][((kc*4 + wn*2 + 1)*64 + l)*8];
      acc[0][0] = __builtin_amdgcn_mfma_f32_16x16x32_bf16(a0, b0, acc[0][0], 0,0,0);
      acc[1][0] = __builtin_amdgcn_mfma_f32_16x16x32_bf16(a1, b0, acc[1][0], 0,0,0);
      acc[2][0] = __builtin_amdgcn_mfma_f32_16x16x32_bf16(a2, b0, acc[2][0], 0,0,0);
      acc[3][0] = __builtin_amdgcn_mfma_f32_16x16x32_bf16(a3, b0, acc[3][0], 0,0,0);
      acc[0][1] = __builtin_amdgcn_mfma_f32_16x16x32_bf16(a0, b1, acc[0][1], 0,0,0);
      acc[1][1] = __builtin_amdgcn_mfma_f32_16x16x32_bf16(a1, b1, acc[1][1], 0,0,0);
      acc[2][1] = __builtin_amdgcn_mfma_f32_16x16x32_bf16(a2, b1, acc[2][1], 0,0,0);
      acc[3][1] = __builtin_amdgcn_mfma_f32_16x16x32_bf16(a3, b1, acc[3][1], 0,0,0);
    }
    __syncthreads();
    buf ^= 1;
  }

  const int r0 = (l>>4)*4, cl = l&15;
  float* ob = outp + (size_t)(cot*128 + wm*64)*N + pos0 + wn*32 + cl;
  #pragma unroll
  for (int mf=0; mf<4; ++mf)
    #pragma unroll
    for (int nf=0; nf<2; ++nf){
      float* op = ob + (size_t)(mf*16 + r0)*N + nf*16;
      #pragma unroll
      for (int i=0;i<4;++i) op[(size_t)i*N] = acc[mf][nf][i];
    }
}

// ---------------------------------------------------------------------------
// 4) inverse feature norms per position
__global__ void k_invnorm(float* __restrict__ ws){
  int id = blockIdx.x*256 + threadIdx.x;
  if (id >= 10752) return;
  int tsr = id / 5376, r = id % 5376;
  int P, q; size_t fbase;
  if (r < 256)     { P=64;   q=r;      fbase = tsr ? OFF_TF8  : OFF_SF8; }
  else if (r<1280) { P=256;  q=r-256;  fbase = tsr ? OFF_TF16 : OFF_SF16; }
  else             { P=1024; q=r-1280; fbase = tsr ? OFF_TF32 : OFF_SF32; }
  int b = q / P, pos = q % P;
  const float* f = ws + fbase + (size_t)b*256*P + pos;
  float s = 0.f;
  for (int ch=0; ch<256; ch++){ float v = f[(size_t)ch*P]; s = fmaf(v,v,s); }
  ws[(tsr ? OFF_INVT : OFF_INVS) + r] = 1.f/sqrtf(s);
}

// ---------------------------------------------------------------------------
// 5) all 9 normalized-correlation GEMMs (f32), 64x64 tiles, K=256
__global__ __launch_bounds__(256) void k_corr(float* __restrict__ ws){
  int bx = blockIdx.x;
  int p = (bx>=4)+(bx>=20)+(bx>=84)+(bx>=100)+(bx>=164)+(bx>=420)+(bx>=484)+(bx>=740);
  int si = p/3, ti = p%3;
  int M = SSARR[si]*SSARR[si], N = SSARR[ti]*SSARR[ti];
  int ntN = N >> 6;
  int rem = bx - PAIR_START[p];
  int b = rem & 3; rem >>= 2;
  int nt = rem % ntN, mt = rem / ntN;
  int m0 = mt*64, n0 = nt*64;
  const float* A  = ws + (si==0?OFF_SF8: si==1?OFF_SF16:OFF_SF32) + (size_t)b*256*M;
  const float* Bp = ws + (ti==0?OFF_TF8: ti==1?OFF_TF16:OFF_TF32) + (size_t)b*256*N;
  const float* iS = ws + OFF_INVS + (si==0?0: si==1?256:1280) + (size_t)b*M;
  const float* iT = ws + OFF_INVT + (ti==0?0: ti==1?256:1280) + (size_t)b*N;
  float* C = ws + PAIR_OFF[p] + (size_t)b*M*N;
  __shared__ __align__(16) float As[16][64];
  __shared__ __align__(16) float Bs[16][64];
  int t = threadIdx.x, tm = t>>4, tn = t&15;
  float acc[4][4] = {};
  #pragma unroll 1
  for (int k0=0; k0<256; k0+=16){
    __syncthreads();
    #pragma unroll
    for (int i=0;i<4;i++){
      int idx = t + i*256; int k = idx>>6, m = idx&63;
      As[k][m] = A [(size_t)(k0+k)*M + m0+m];
      Bs[k][m] = Bp[(size_t)(k0+k)*N + n0+m];
    }
    __syncthreads();
    #pragma unroll
    for (int k=0;k<16;k++){
      float4 av = *reinterpret_cast<const float4*>(&As[k][tm*4]);
      float4 bv = *reinterpret_cast<const float4*>(&Bs[k][tn*4]);
      float a4[4]={av.x,av.y,av.z,av.w}, b4[4]={bv.x,bv.y,bv.z,bv.w};
      #pragma unroll
      for (int i=0;i<4;i++)
        #pragma unroll
        for (int j=0;j<4;j++)
          acc[i][j] = fmaf(a4[i], b4[j], acc[i][j]);
    }
  }
  #pragma unroll
  for (int i=0;i<4;i++){
    float sv = iS[m0+tm*4+i];
    #pragma unroll
    for (int j=0;j<4;j++)
      C[(size_t)(m0+tm*4+i)*N + n0+tn*4+j] = acc[i][j]*sv*iT[n0+tn*4+j];
  }
}

// ---------------------------------------------------------------------------
DEVFN void cw_coord(int i, int n, int OH, int& i0, int& i1, float& f){
  float c = (float)(i*(n-1))/(float)(OH-1);
  int a = (int)c; if (a > n-1) a = n-1;
  i0 = a; i1 = (a+1 < n) ? a+1 : n-1; f = c - (float)a;
}

// 6) interp_pairs v2: block = (p,b,oy,ox); stage 4 corner (y,x) planes in LDS
__global__ __launch_bounds__(256) void k_interp_pairs(float* __restrict__ ws){
  int bx = blockIdx.x;
  int p = bx >> 10;
  int bl = bx & 1023;                    // [b:2][oy:4][ox:4]
  int b = bl >> 8, oy = (bl >> 4) & 15, ox = bl & 15;
  int si = p/3, ti = p%3;
  int h1 = SSARR[si], t1 = SSARR[ti], t12 = t1*t1;
  int y0,y1,x0,x1; float fy,fx;
  cw_coord(oy,h1,16,y0,y1,fy); cw_coord(ox,h1,16,x0,x1,fx);
  const float* in = ws + PAIR_OFF[p] + (size_t)b*h1*h1*t12;
  __shared__ float sPl[4][1024];
  const int t = threadIdx.x;
  {
    const float* pl0 = in + (size_t)(y0*h1+x0)*t12;
    const float* pl1 = in + (size_t)(y0*h1+x1)*t12;
    const float* pl2 = in + (size_t)(y1*h1+x0)*t12;
    const float* pl3 = in + (size_t)(y1*h1+x1)*t12;
    for (int i=t; i<t12; i+=256){
      sPl[0][i] = pl0[i]; sPl[1][i] = pl1[i];
      sPl[2][i] = pl2[i]; sPl[3][i] = pl3[i];
    }
  }
  __syncthreads();
  int px = t & 15, py = t >> 4;
  int u0,u1,v0,v1; float fu,fv;
  cw_coord(py,t1,16,u0,u1,fu); cw_coord(px,t1,16,v0,v1,fv);
  float wY[2]={1.f-fy,fy}, wX[2]={1.f-fx,fx};
  float wU[2]={1.f-fu,fu}, wV[2]={1.f-fv,fv};
  int us[2]={u0,u1}, vs[2]={v0,v1};
  float s = 0.f;
  #pragma unroll
  for (int qa=0; qa<2; qa++)
    #pragma unroll
    for (int qc=0; qc<2; qc++){
      float wyx = wY[qa]*wX[qc];
      const float* base = sPl[qa*2+qc];
      #pragma unroll
      for (int qu=0; qu<2; qu++)
        #pragma unroll
        for (int qv=0; qv<2; qv++)
          s += wyx*wU[qu]*wV[qv]*base[us[qu]*t1 + vs[qv]];
    }
  ws[OFF_CORR6 + ((size_t)b*9 + p)*65536 + ((size_t)(oy*16+ox)<<8) + t] = fmaxf(s, 0.f);
}

// ---------------------------------------------------------------------------
// 7) chm6d v5: software-pipelined dbuf plane staging (write pr+1 before
//    computing pr), per-wave private LDS (no barriers), 4-way (a,c) parity,
//    contiguous packed weights (batched s_loads). Writes partials.
__global__ __launch_bounds__(256) void k_chm6d(float* __restrict__ ws,
                                               const float* __restrict__ k6p){
  const int bx = blockIdx.x;                 // 1024 = g*256 + sy*16 + sx
  const int g = bx >> 8, sy = (bx>>4)&15, sx = bx&15;
  const int t = threadIdx.x;
  const int bq = t>>6, l = t&63, ty = l>>2, tx = l&3;
  __shared__ __align__(16) float sP[4][2][560];   // per-wave dbuf 20x28, 17.9KB
  float* const PB0 = &sP[bq][0][0];
  float* const PB1 = &sP[bq][1][0];
  for (int i=l; i<560; i+=64){ PB0[i]=0.f; PB1[i]=0.f; }  // borders stay zero
  f32x4 acc[9];
  #pragma unroll
  for (int i=0;i<9;i++) acc[i] = (f32x4){0.f,0.f,0.f,0.f};
  const float* c6 = ws + OFF_CORR6 + (size_t)bq*9*65536;
  const int wo = (2+ty)*28 + 2 + 4*tx;           // interior write offset
  #pragma unroll 1
  for (int a=0; a<5; a++){
    int Y = sy+a-2; if (Y<0 || Y>15) continue;
    #pragma unroll 1
    for (int c=0; c<5; c++){
      if (((a*5+c)&3) != g) continue;
      int X = sx+c-2; if (X<0 || X>15) continue;
      const float* pb = c6 + (size_t)(Y*16+X)*256 + l*4;
      const float* wac = k6p + (size_t)(a*5+c)*2160;   // [pr][d][48]
      float4 pf = *reinterpret_cast<const float4*>(pb);            // plane 0
      { float* wp = PB0 + wo;
        *reinterpret_cast<float2*>(wp)   = make_float2(pf.x, pf.y);
        *reinterpret_cast<float2*>(wp+2) = make_float2(pf.z, pf.w); }
      pf = *reinterpret_cast<const float4*>(pb + 65536);           // plane 1
      #pragma unroll
      for (int pr=0; pr<9; pr++){
        const int pi = pr/3, pj = pr%3;
        float* const cur = (pr&1) ? PB1 : PB0;
        if (pr < 8){                       // publish NEXT plane before compute
          float* wp = ((pr&1) ? PB0 : PB1) + wo;
          *reinterpret_cast<float2*>(wp)   = make_float2(pf.x, pf.y);
          *reinterpret_cast<float2*>(wp+2) = make_float2(pf.z, pf.w);
          if (pr < 7)
            pf = *reinterpret_cast<const float4*>(pb + (size_t)(pr+2)*65536);
        }
        const float* wpr = wac + pr*240;   // [d][48]
        #pragma unroll 1
        for (int d=0; d<5; d++){
          const float* rp = cur + (ty+d)*28 + 4*tx;                // 16B aligned
          float4 q0 = *reinterpret_cast<const float4*>(rp);
          float4 q1 = *reinterpret_cast<const float4*>(rp+4);
          float r8[8] = {q0.x,q0.y,q0.z,q0.w,q1.x,q1.y,q1.z,q1.w};
          const float* wb = wpr + d*48;    // 45 contiguous weights (uniform)
          #pragma unroll
          for (int ki=0; ki<3; ki++){
            const int sio = pi-ki+1; if (sio<0 || sio>2) continue;
            #pragma unroll
            for (int kj=0; kj<3; kj++){
              const int sjo = pj-kj+1; if (sjo<0 || sjo>2) continue;
              const float* we = wb + (ki*3+kj)*5;
              #pragma unroll
              for (int e=0; e<5; e++)
                #pragma unroll
                for (int xi=0; xi<4; xi++)
                  acc[sio*3+sjo][xi] = fmaf(r8[e+xi], we[e], acc[sio*3+sjo][xi]);
            }
          }
        }
      }
    }
  }
  float* po = ws + OFF_PART + ((size_t)(g*4+bq)*9)*65536
            + (size_t)(sy*16+sx)*256 + ty*16 + tx*4;
  #pragma unroll
  for (int so=0; so<9; so++)
    *reinterpret_cast<f32x4*>(po + (size_t)so*65536) = acc[so];
}

// 7b) combine 4 parity partials + sigmoid + max over 9 so
__global__ void k_sigmax(float* __restrict__ ws){
  int id = blockIdx.x*256 + threadIdx.x;        // 4*65536
  int b = id >> 16, pos = id & 65535;
  const float* p = ws + OFF_PART + (size_t)b*589824 + pos;   // [g][b][so][pos]
  float m = -1e30f;
  #pragma unroll
  for (int so=0; so<9; so++){
    size_t o = (size_t)so*65536;
    float s = p[o] + p[o+2359296] + p[o+2u*2359296] + p[o+3u*2359296];
    m = fmaxf(m, s);
  }
  ws[OFF_MAXED + (size_t)b*65536 + pos] = 1.f/(1.f + expf(-m));
}

// ---------------------------------------------------------------------------
// 8) interpolate4d 16^4 -> 32^4
__global__ void k_interp32(float* __restrict__ ws){
  int id = blockIdx.x*256 + threadIdx.x;
  int px = id & 31, py = (id>>5)&31, ox = (id>>10)&31, oy = (id>>15)&31, b = id>>20;
  int y0,y1,x0,x1,u0,u1,v0,v1; float fy,fx,fu,fv;
  cw_coord(oy,16,32,y0,y1,fy); cw_coord(ox,16,32,x0,x1,fx);
  cw_coord(py,16,32,u0,u1,fu); cw_coord(px,16,32,v0,v1,fv);
  const float* in = ws + OFF_MAXED + (size_t)b*65536;
  int ys[2]={y0,y1}, xs[2]={x0,x1}, us[2]={u0,u1}, vs[2]={v0,v1};
  float wy[2]={1.f-fy,fy}, wx[2]={1.f-fx,fx}, wu[2]={1.f-fu,fu}, wv[2]={1.f-fv,fv};
  float s = 0.f;
  #pragma unroll
  for (int ia=0; ia<2; ia++)
    #pragma unroll
    for (int ic=0; ic<2; ic++){
      float wyx = wy[ia]*wx[ic];
      const float* base = in + ((size_t)ys[ia]*16 + xs[ic])*256;
      #pragma unroll
      for (int id_=0; id_<2; id_++)
        #pragma unroll
        for (int ie=0; ie<2; ie++)
          s += wyx*wu[id_]*wv[ie]*base[(size_t)us[id_]*16 + vs[ie]];
    }
  ws[OFF_INT32 + id] = s;
}

// ---------------------------------------------------------------------------
// 9) fast4d v3 (R7): 4 sx-outputs/block, dbuf plane staging, reg prefetch
__global__ __launch_bounds__(256) void k_fast4d(float* __restrict__ ws,
                                                const float* __restrict__ k4,
                                                const float* __restrict__ b4,
                                                float* __restrict__ out){
  const int b = blockIdx.y;
  const int sy = blockIdx.x >> 3, sx0 = (blockIdx.x & 7) << 2;
  const int t = threadIdx.x;
  const int y = t >> 3, x0 = (t & 7) << 2;
  __shared__ __align__(16) float sQ[2][36*48];
  for (int i=t; i<1728; i+=256){ sQ[0][i]=0.f; sQ[1][i]=0.f; }
  __syncthreads();
  const float* in = ws + OFF_INT32 + (size_t)b*1048576;
  float acc[4][4] = {};

  int i0 = 0;
  for (; i0 < 40; ++i0){
    int Y = sy + (i0>>3) - 2, X = sx0 - 2 + (i0&7);
    if (Y>=0 && Y<=31 && X>=0 && X<=31) break;
  }
  float4 pf = make_float4(0.f,0.f,0.f,0.f);
  if (i0 < 40){
    int Y = sy + (i0>>3) - 2, X = sx0 - 2 + (i0&7);
    pf = *reinterpret_cast<const float4*>(in + (size_t)(Y*32+X)*1024 + t*4);
  }
  int cur = 0, i = i0;
  const int srow = t >> 3, scol4 = (t & 7) << 2;
  #pragma unroll 1
  while (i < 40){
    int nx = i+1;
    for (; nx < 40; ++nx){
      int Y = sy + (nx>>3) - 2, X = sx0 - 2 + (nx&7);
      if (Y>=0 && Y<=31 && X>=0 && X<=31) break;
    }
    float* wp = &sQ[cur][(2+srow)*48 + 2 + scol4];
    wp[0]=pf.x; wp[1]=pf.y; wp[2]=pf.z; wp[3]=pf.w;
    if (nx < 40){
      int Y = sy + (nx>>3) - 2, X = sx0 - 2 + (nx&7);
      pf = *reinterpret_cast<const float4*>(in + (size_t)(Y*32+X)*1024 + t*4);
    }
    __syncthreads();
    const int a = i>>3, Xi = i&7;
    const float* ka = k4 + a*125;
    #pragma unroll
    for (int d=0; d<5; d++){
      const float* row = &sQ[cur][(y+d)*48 + x0];
      float4 q0 = *reinterpret_cast<const float4*>(row);
      float4 q1 = *reinterpret_cast<const float4*>(row+4);
      float r8[8] = {q0.x,q0.y,q0.z,q0.w,q1.x,q1.y,q1.z,q1.w};
      #pragma unroll
      for (int j=0; j<4; j++){
        const int c = Xi - j;
        if (c >= 0 && c <= 4){
          const float* kc = ka + c*25 + d*5;
          #pragma unroll
          for (int e=0; e<5; e++){
            float wv = kc[e];
            #pragma unroll
            for (int xi=0; xi<4; xi++)
              acc[j][xi] = fmaf(r8[xi+e], wv, acc[j][xi]);
          }
        }
      }
    }
    cur ^= 1; i = nx;
  }
  float bias = b4[0];
  #pragma unroll
  for (int j=0; j<4; j++){
    float4 o;
    float* po = &o.x;
    #pragma unroll
    for (int xi=0; xi<4; xi++){
      float xv = acc[j][xi] + bias;
      po[xi] = fmaxf(xv,0.f) + log1pf(expf(-fabsf(xv)));
    }
    *reinterpret_cast<float4*>(
      out + ((size_t)b*1024 + sy*32 + sx0 + j)*1024 + y*32 + x0) = o;
  }
}

// ---------------------------------------------------------------------------
// 10-12) mutual_nn_filter
__global__ void k_rowmax(const float* __restrict__ cm, float* __restrict__ ws){
  int row = blockIdx.x;
  const float* r = cm + (size_t)row*1024;
  int t = threadIdx.x;
  float m = -1e30f;
  for (int i=t; i<1024; i+=256) m = fmaxf(m, r[i]);
  __shared__ float red[256];
  red[t] = m; __syncthreads();
  for (int off=128; off; off>>=1){
    if (t < off) red[t] = fmaxf(red[t], red[t+off]);
    __syncthreads();
  }
  if (!t) ws[OFF_SMAX + row] = red[0];
}

__global__ void k_colmax_p(const float* __restrict__ cm, float* __restrict__ ws){
  int b = blockIdx.x >> 5, rg = (blockIdx.x >> 2) & 7, cg = blockIdx.x & 3;
  int c = cg*256 + threadIdx.x;
  const float* base = cm + (size_t)b*1048576 + (size_t)rg*131072 + c;
  float m = -1e30f;
  #pragma unroll 4
  for (int r=0; r<128; r++) m = fmaxf(m, base[(size_t)r*1024]);
  ws[OFF_CMAXP + (size_t)(b*8+rg)*1024 + c] = m;
}

__global__ void k_colmax_r(float* __restrict__ ws){
  int id = blockIdx.x*256 + threadIdx.x;         // 4096
  int b = id >> 10, c = id & 1023;
  float m = -1e30f;
  #pragma unroll
  for (int rg=0; rg<8; rg++)
    m = fmaxf(m, ws[OFF_CMAXP + (size_t)(b*8+rg)*1024 + c]);
  ws[OFF_TMAX + id] = m;
}

__global__ void k_mutual(float* __restrict__ cm, const float* __restrict__ ws){
  int id = blockIdx.x*256 + threadIdx.x;
  int b = id >> 20, r = (id>>10)&1023, c = id&1023;
  float v  = cm[id];
  float sm = ws[OFF_SMAX + (b<<10) + r];
  float tm = ws[OFF_TMAX + (b<<10) + c];
  sm = (sm==0.f) ? 1e-30f : sm;
  tm = (tm==0.f) ? 1e-30f : tm;
  cm[id] = v * (v/sm) * (v/tm);
}

// ---------------------------------------------------------------------------
extern "C" void kernel_launch(void* const* d_in, const int* in_sizes, int n_in,
                              void* d_out, int out_size, void* d_ws, size_t ws_size,
                              hipStream_t stream){
  const float* src = (const float*)d_in[0];
  const float* trg = (const float*)d_in[1];
  const float* w0  = (const float*)d_in[2];
  const float* w1  = (const float*)d_in[3];
  const float* w2  = (const float*)d_in[4];
  const float* k6  = (const float*)d_in[5];
  const float* k4  = (const float*)d_in[6];
  const float* b4  = (const float*)d_in[7];
  float* ws  = (float*)d_ws;    // needs WS_FLOATS*4 = ~61 MB
  float* out = (float*)d_out;
  (void)in_sizes; (void)n_in; (void)out_size; (void)ws_size;

  k_wpack       <<<3456,  256, 0, stream>>>(w0, w1, w2, ws);
  k_k6p         <<<211,   256, 0, stream>>>(k6, ws);
  k_inpack      <<<512,   256, 0, stream>>>(src, trg, ws);
  k_conv_mfma   <<<336,   256, 0, stream>>>(ws);
  k_invnorm     <<<42,    256, 0, stream>>>(ws);
  k_corr        <<<1764,  256, 0, stream>>>(ws);
  k_interp_pairs<<<9216,  256, 0, stream>>>(ws);
  k_chm6d       <<<1024,  256, 0, stream>>>(ws, ws + OFF_K6P);
  k_sigmax      <<<1024,  256, 0, stream>>>(ws);
  k_interp32    <<<16384, 256, 0, stream>>>(ws);
  k_fast4d      <<<dim3(256,4),  256, 0, stream>>>(ws, k4, b4, out);
  k_rowmax      <<<4096,  256, 0, stream>>>(out, ws);
  k_colmax_p    <<<128,   256, 0, stream>>>(out, ws);
  k_colmax_r    <<<16,    256, 0, stream>>>(ws);
  k_mutual      <<<16384, 256, 0, stream>>>(out, ws);
}

// Round 10
// 602.020 us; speedup vs baseline: 1.0122x; 1.0122x over previous
//
#include <hip/hip_runtime.h>
#include <cstdint>
#include <cstddef>

// ============================================================================
// CHMLearner forward. R10: chm6d v6 — conflict-free LDS (stride 48 ≡ 16 mod 32;
// all aligned b128 access; per-8-lane groups cover all 8 16B bank slots).
// Keeps v5's per-pr double-buffer + reg prefetch + packed weights.
// Rest identical to R9.
// ============================================================================

#define DEVFN __device__ __forceinline__

typedef __attribute__((ext_vector_type(8))) short short8v;
typedef __attribute__((ext_vector_type(4))) float f32x4;
typedef unsigned int u32;

DEVFN void gl_lds16(const void* g, void* l){
  __builtin_amdgcn_global_load_lds(
      (const __attribute__((address_space(1))) u32*)g,
      (__attribute__((address_space(3))) u32*)l, 16, 0, 0);
}

// workspace layout (float units). Total ~61 MB
constexpr size_t OFF_WB    = 0;           // bf16 packed weights, 3*2,359,296 bf16
constexpr size_t OFF_P8    = 3538944;     // bf16 padded ch-last features
constexpr size_t OFF_P16   = 3948544;
constexpr size_t OFF_P32   = 5275648;
constexpr size_t OFF_SF8   = 10010624;    // conv outputs f32 [b][256][S*S]
constexpr size_t OFF_TF8   = 10076160;
constexpr size_t OFF_SF16  = 10141696;
constexpr size_t OFF_TF16  = 10403840;
constexpr size_t OFF_SF32  = 10665984;
constexpr size_t OFF_TF32  = 11714560;
constexpr size_t OFF_INVS  = 12763136;
constexpr size_t OFF_INVT  = 12768512;
constexpr size_t OFF_SMAX  = 12773888;
constexpr size_t OFF_TMAX  = 12777984;
constexpr size_t OFF_CORR6 = 12782080;    // [4][9][16^4]
constexpr size_t OFF_CMAXP = OFF_CORR6 + 2359296 + 128;   // 32768 colmax partials
constexpr size_t OFF_K6P   = OFF_CMAXP + 32768;           // 54000 packed 6d weights
constexpr size_t WS_FLOATS = OFF_K6P + 54016;

// aliases into dead regions (all of [0, 10,010,624) is dead post-corr):
__device__ constexpr size_t PAIR_OFF[9] = {   // raw per-pair corr [4][ss^2][ts^2]
  OFF_WB + 0,       OFF_WB + 16384,   OFF_WB + 81920,
  OFF_WB + 344064,  OFF_WB + 409600,  OFF_WB + 671744,
  OFF_WB + 1720320, OFF_WB + 1982464, OFF_WB + 3031040 };
constexpr size_t OFF_PART  = 0;            // [4g][4b][9so][16^4] = 9,437,184 floats
constexpr size_t OFF_MAXED = 9437184;      // [4][16^4]
constexpr size_t OFF_INT32 = 262144;       // [4][32^4] (PART dead by interp32 time)

__device__ constexpr int SSARR[3] = {8, 16, 32};
__device__ constexpr int PAIR_START[9] = {0,4,20,84,100,164,420,484,740}; // 1764

DEVFN unsigned short f2bf(float f){
  unsigned int u = __float_as_uint(f);
  return (unsigned short)((u + 0x7fffu + ((u >> 16) & 1u)) >> 16);
}

// ---------------------------------------------------------------------------
// 1) pack conv weights into MFMA A-fragment order (bf16)
__global__ void k_wpack(const float* __restrict__ w0, const float* __restrict__ w1,
                        const float* __restrict__ w2, float* __restrict__ wsf){
  int gid = blockIdx.x*256 + threadIdx.x;        // 884,736 exact
  int scale = gid / 294912, r = gid % 294912;
  int tap = r >> 15, kc = (r>>10)&31, nc = (r>>6)&15, l = r&63;
  const float* w = (scale==0) ? w0 : (scale==1 ? w1 : w2);
  int co = nc*16 + (l&15);
  int ci0 = kc*32 + ((l>>4)&3)*8;
  unsigned short* o = (unsigned short*)(wsf + OFF_WB) + (size_t)gid*8;
  #pragma unroll
  for (int i=0;i<8;i++)
    o[i] = f2bf(w[((size_t)co*1024 + ci0 + i)*9 + tap]);
}

// 1b) pack chm6d weights: K6P[(a*5+c)][pr][d][48] ; slot s=ki*3+kj, j=s*5+e
__global__ void k_k6p(const float* __restrict__ k6, float* __restrict__ ws){
  int gid = blockIdx.x*256 + threadIdx.x;        // 54,000
  if (gid >= 54000) return;
  int ac = gid / 2160, r = gid % 2160;
  int r2 = r % 240;
  int d = r2 / 48, j = r2 % 48;
  float v = 0.f;
  if (j < 45){
    int s = j/5, e = j%5;
    int a = ac/5, c = ac%5;
    v = k6[(((s*5 + a)*5 + c)*5 + d)*5 + e];
  }
  ws[OFF_K6P + gid] = v;
}

// ---------------------------------------------------------------------------
// 2) inpack: stage 16 channels' 16x16 planes in LDS; emit all 3 scales
__global__ __launch_bounds__(256) void k_inpack(const float* __restrict__ src,
                                                const float* __restrict__ trg,
                                                float* __restrict__ wsf){
  int bt = blockIdx.x >> 6, cg = blockIdx.x & 63;
  int chbase = cg*16;
  int t = threadIdx.x;
  __shared__ float sIn[16][257];
  const float* gin = ((bt>=4)? trg : src) + ((size_t)(bt&3)*1024 + chbase)*256;
  #pragma unroll
  for (int i=0;i<16;i++){
    int idx = t + i*256; int ch = idx>>8, pos = idx&255;
    sIn[ch][pos] = gin[(size_t)ch*256 + pos];
  }
  __syncthreads();
  int ch = t & 15, pw = t >> 4;
  #pragma unroll 1
  for (int s=0; s<3; s++){
    int S = SSARR[s], Sp = S+2, Sp2 = Sp*Sp;
    size_t poff = (s==0)?OFF_P8 : (s==1)?OFF_P16 : OFF_P32;
    unsigned short* o = (unsigned short*)(wsf + poff) + (size_t)bt*Sp2*1024 + chbase + ch;
    float rs = 15.f/(float)(S-1);
    for (int i = pw; i < Sp2; i += 16){
      int py = i / Sp, px = i % Sp;
      float v = 0.f;
      if (py>0 && py<Sp-1 && px>0 && px<Sp-1){
        float cy = (float)(py-1)*rs, cx = (float)(px-1)*rs;
        int y0 = (int)cy; if (y0>15) y0=15; int y1 = (y0+1<16)?y0+1:15; float fy = cy-(float)y0;
        int x0 = (int)cx; if (x0>15) x0=15; int x1 = (x0+1<16)?x0+1:15; float fx = cx-(float)x0;
        v = (1.f-fy)*((1.f-fx)*sIn[ch][y0*16+x0] + fx*sIn[ch][y0*16+x1])
          +       fy*((1.f-fx)*sIn[ch][y1*16+x0] + fx*sIn[ch][y1*16+x1]);
      }
      o[(size_t)i*1024] = f2bf(v);
    }
  }
}

// ---------------------------------------------------------------------------
// 3) conv3x3 as bf16 MFMA GEMM with LDS double-buffer + global_load_lds.
__global__ __launch_bounds__(256) void k_conv_mfma(float* __restrict__ wsf){
  int bx = (blockIdx.x & 7)*42 + (blockIdx.x >> 3);   // bijective, 336 blocks
  int scale, bt, cot, post, S, lgS;
  if (bx < 256)      { scale=2; S=32; lgS=5; bt=bx>>5; cot=(bx>>4)&1; post=bx&15; }
  else if (bx < 320) { int r=bx-256; scale=1; S=16; lgS=4; bt=r>>3; cot=(r>>2)&1; post=r&3; }
  else               { int r=bx-320; scale=0; S=8;  lgS=3; bt=r>>1; cot=r&1; post=0; }
  const int Sp = S+2, N = S*S;
  const unsigned short* WbS = (const unsigned short*)(wsf + OFF_WB) + (size_t)scale*2359296;
  size_t poff = scale==0?OFF_P8: scale==1?OFF_P16:OFF_P32;
  const unsigned short* Pb = (const unsigned short*)(wsf + poff) + (size_t)bt*Sp*Sp*1024;
  size_t obase = (scale==2) ? (bt>=4?OFF_TF32:OFF_SF32)
               : (scale==1) ? (bt>=4?OFF_TF16:OFF_SF16)
                            : (bt>=4?OFF_TF8 :OFF_SF8);
  float* outp = wsf + obase + (size_t)(bt&3)*256*N;

  const int t = threadIdx.x, l = t&63, w = t>>6, wm = w&1, wn = w>>1;
  const int nc_base = cot*8;
  const int pos0 = post*64;

  __shared__ __align__(16) unsigned short Ab[2][8192];   // 32 KB
  __shared__ __align__(16) unsigned short Bb[2][4096];   // 16 KB

  f32x4 acc[4][2];
  #pragma unroll
  for (int i=0;i<4;i++)
    #pragma unroll
    for (int j=0;j<2;j++) acc[i][j] = (f32x4){0.f,0.f,0.f,0.f};

  auto STAGE = [&](int buf, int it){
    int tap = it>>4, kq = it&15;
    int dy = tap/3, dx = tap - dy*3;
    #pragma unroll
    for (int j=0;j<4;++j){
      int c = w + j*4;
      int kc = c>>3, nc = c&7;
      const unsigned short* src =
        WbS + ((((size_t)tap*32 + kq*2 + kc)*16 + nc_base + nc)*64 + l)*8;
      gl_lds16(src, &Ab[buf][c*512]);
    }
    #pragma unroll
    for (int j=0;j<2;++j){
      int c = w + j*4;
      int kc = c>>2, np = c&3;
      int pos = pos0 + np*16 + (l&15);
      int y = pos>>lgS, x = pos&(S-1);
      int row = (y+dy)*Sp + (x+dx);
      int ci = kq*64 + kc*32 + ((l>>4)<<3);
      gl_lds16(Pb + (size_t)row*1024 + ci, &Bb[buf][c*512]);
    }
  };

  STAGE(0, 0);
  __syncthreads();
  int buf = 0;
  #pragma unroll 1
  for (int it=0; it<144; ++it){
    if (it+1 < 144) STAGE(buf^1, it+1);
    #pragma unroll
    for (int kc=0; kc<2; ++kc){
      short8v a0 = *(const short8v*)&Ab[buf][((kc*8 + wm*4 + 0)*64 + l)*8];
      short8v a1 = *(const short8v*)&Ab[buf][((kc*8 + wm*4 + 1)*64 + l)*8];
      short8v a2 = *(const short8v*)&Ab[buf][((kc*8 + wm*4 + 2)*64 + l)*8];
      short8v a3 = *(const short8v*)&Ab[buf][((kc*8 + wm*4 + 3)*64 + l)*8];
      short8v b0 = *(const short8v*)&Bb[buf][((kc*4 + wn*2 + 0)*64 + l)*8];
      short8v b1 = *(const short8v*)&Bb[buf][((kc*4 + wn*2 + 1)*64 + l)*8];
      acc[0][0] = __builtin_amdgcn_mfma_f32_16x16x32_bf16(a0, b0, acc[0][0], 0,0,0);
      acc[1][0] = __builtin_amdgcn_mfma_f32_16x16x32_bf16(a1, b0, acc[1][0], 0,0,0);
      acc[2][0] = __builtin_amdgcn_mfma_f32_16x16x32_bf16(a2, b0, acc[2][0], 0,0,0);
      acc[3][0] = __builtin_amdgcn_mfma_f32_16x16x32_bf16(a3, b0, acc[3][0], 0,0,0);
      acc[0][1] = __builtin_amdgcn_mfma_f32_16x16x32_bf16(a0, b1, acc[0][1], 0,0,0);
      acc[1][1] = __builtin_amdgcn_mfma_f32_16x16x32_bf16(a1, b1, acc[1][1], 0,0,0);
      acc[2][1] = __builtin_amdgcn_mfma_f32_16x16x32_bf16(a2, b1, acc[2][1], 0,0,0);
      acc[3][1] = __builtin_amdgcn_mfma_f32_16x16x32_bf16(a3, b1, acc[3][1], 0,0,0);
    }
    __syncthreads();
    buf ^= 1;
  }

  const int r0 = (l>>4)*4, cl = l&15;
  float* ob = outp + (size_t)(cot*128 + wm*64)*N + pos0 + wn*32 + cl;
  #pragma unroll
  for (int mf=0; mf<4; ++mf)
    #pragma unroll
    for (int nf=0; nf<2; ++nf){
      float* op = ob + (size_t)(mf*16 + r0)*N + nf*16;
      #pragma unroll
      for (int i=0;i<4;++i) op[(size_t)i*N] = acc[mf][nf][i];
    }
}

// ---------------------------------------------------------------------------
// 4) inverse feature norms per position
__global__ void k_invnorm(float* __restrict__ ws){
  int id = blockIdx.x*256 + threadIdx.x;
  if (id >= 10752) return;
  int tsr = id / 5376, r = id % 5376;
  int P, q; size_t fbase;
  if (r < 256)     { P=64;   q=r;      fbase = tsr ? OFF_TF8  : OFF_SF8; }
  else if (r<1280) { P=256;  q=r-256;  fbase = tsr ? OFF_TF16 : OFF_SF16; }
  else             { P=1024; q=r-1280; fbase = tsr ? OFF_TF32 : OFF_SF32; }
  int b = q / P, pos = q % P;
  const float* f = ws + fbase + (size_t)b*256*P + pos;
  float s = 0.f;
  for (int ch=0; ch<256; ch++){ float v = f[(size_t)ch*P]; s = fmaf(v,v,s); }
  ws[(tsr ? OFF_INVT : OFF_INVS) + r] = 1.f/sqrtf(s);
}

// ---------------------------------------------------------------------------
// 5) all 9 normalized-correlation GEMMs (f32), 64x64 tiles, K=256
__global__ __launch_bounds__(256) void k_corr(float* __restrict__ ws){
  int bx = blockIdx.x;
  int p = (bx>=4)+(bx>=20)+(bx>=84)+(bx>=100)+(bx>=164)+(bx>=420)+(bx>=484)+(bx>=740);
  int si = p/3, ti = p%3;
  int M = SSARR[si]*SSARR[si], N = SSARR[ti]*SSARR[ti];
  int ntN = N >> 6;
  int rem = bx - PAIR_START[p];
  int b = rem & 3; rem >>= 2;
  int nt = rem % ntN, mt = rem / ntN;
  int m0 = mt*64, n0 = nt*64;
  const float* A  = ws + (si==0?OFF_SF8: si==1?OFF_SF16:OFF_SF32) + (size_t)b*256*M;
  const float* Bp = ws + (ti==0?OFF_TF8: ti==1?OFF_TF16:OFF_TF32) + (size_t)b*256*N;
  const float* iS = ws + OFF_INVS + (si==0?0: si==1?256:1280) + (size_t)b*M;
  const float* iT = ws + OFF_INVT + (ti==0?0: ti==1?256:1280) + (size_t)b*N;
  float* C = ws + PAIR_OFF[p] + (size_t)b*M*N;
  __shared__ __align__(16) float As[16][64];
  __shared__ __align__(16) float Bs[16][64];
  int t = threadIdx.x, tm = t>>4, tn = t&15;
  float acc[4][4] = {};
  #pragma unroll 1
  for (int k0=0; k0<256; k0+=16){
    __syncthreads();
    #pragma unroll
    for (int i=0;i<4;i++){
      int idx = t + i*256; int k = idx>>6, m = idx&63;
      As[k][m] = A [(size_t)(k0+k)*M + m0+m];
      Bs[k][m] = Bp[(size_t)(k0+k)*N + n0+m];
    }
    __syncthreads();
    #pragma unroll
    for (int k=0;k<16;k++){
      float4 av = *reinterpret_cast<const float4*>(&As[k][tm*4]);
      float4 bv = *reinterpret_cast<const float4*>(&Bs[k][tn*4]);
      float a4[4]={av.x,av.y,av.z,av.w}, b4[4]={bv.x,bv.y,bv.z,bv.w};
      #pragma unroll
      for (int i=0;i<4;i++)
        #pragma unroll
        for (int j=0;j<4;j++)
          acc[i][j] = fmaf(a4[i], b4[j], acc[i][j]);
    }
  }
  #pragma unroll
  for (int i=0;i<4;i++){
    float sv = iS[m0+tm*4+i];
    #pragma unroll
    for (int j=0;j<4;j++)
      C[(size_t)(m0+tm*4+i)*N + n0+tn*4+j] = acc[i][j]*sv*iT[n0+tn*4+j];
  }
}

// ---------------------------------------------------------------------------
DEVFN void cw_coord(int i, int n, int OH, int& i0, int& i1, float& f){
  float c = (float)(i*(n-1))/(float)(OH-1);
  int a = (int)c; if (a > n-1) a = n-1;
  i0 = a; i1 = (a+1 < n) ? a+1 : n-1; f = c - (float)a;
}

// 6) interp_pairs v2: block = (p,b,oy,ox); stage 4 corner (y,x) planes in LDS
__global__ __launch_bounds__(256) void k_interp_pairs(float* __restrict__ ws){
  int bx = blockIdx.x;
  int p = bx >> 10;
  int bl = bx & 1023;                    // [b:2][oy:4][ox:4]
  int b = bl >> 8, oy = (bl >> 4) & 15, ox = bl & 15;
  int si = p/3, ti = p%3;
  int h1 = SSARR[si], t1 = SSARR[ti], t12 = t1*t1;
  int y0,y1,x0,x1; float fy,fx;
  cw_coord(oy,h1,16,y0,y1,fy); cw_coord(ox,h1,16,x0,x1,fx);
  const float* in = ws + PAIR_OFF[p] + (size_t)b*h1*h1*t12;
  __shared__ float sPl[4][1024];
  const int t = threadIdx.x;
  {
    const float* pl0 = in + (size_t)(y0*h1+x0)*t12;
    const float* pl1 = in + (size_t)(y0*h1+x1)*t12;
    const float* pl2 = in + (size_t)(y1*h1+x0)*t12;
    const float* pl3 = in + (size_t)(y1*h1+x1)*t12;
    for (int i=t; i<t12; i+=256){
      sPl[0][i] = pl0[i]; sPl[1][i] = pl1[i];
      sPl[2][i] = pl2[i]; sPl[3][i] = pl3[i];
    }
  }
  __syncthreads();
  int px = t & 15, py = t >> 4;
  int u0,u1,v0,v1; float fu,fv;
  cw_coord(py,t1,16,u0,u1,fu); cw_coord(px,t1,16,v0,v1,fv);
  float wY[2]={1.f-fy,fy}, wX[2]={1.f-fx,fx};
  float wU[2]={1.f-fu,fu}, wV[2]={1.f-fv,fv};
  int us[2]={u0,u1}, vs[2]={v0,v1};
  float s = 0.f;
  #pragma unroll
  for (int qa=0; qa<2; qa++)
    #pragma unroll
    for (int qc=0; qc<2; qc++){
      float wyx = wY[qa]*wX[qc];
      const float* base = sPl[qa*2+qc];
      #pragma unroll
      for (int qu=0; qu<2; qu++)
        #pragma unroll
        for (int qv=0; qv<2; qv++)
          s += wyx*wU[qu]*wV[qv]*base[us[qu]*t1 + vs[qv]];
    }
  ws[OFF_CORR6 + ((size_t)b*9 + p)*65536 + ((size_t)(oy*16+ox)<<8) + t] = fmaxf(s, 0.f);
}

// ---------------------------------------------------------------------------
// 7) chm6d v6: conflict-free LDS. Per-wave dbuf plane 20 rows x 48 words
//    (stride 48 ≡ 16 mod 32 -> each 8-lane group covers all 8 16B slots).
//    Interior col0 at word 4; per-lane write = 1 aligned b128; reads = 3
//    aligned b128/row (cols 4tx-4..4tx+7, use idx 2..9). Zero barriers,
//    4-way (a,c) parity, packed weights.
__global__ __launch_bounds__(256) void k_chm6d(float* __restrict__ ws,
                                               const float* __restrict__ k6p){
  const int bx = blockIdx.x;                 // 1024 = g*256 + sy*16 + sx
  const int g = bx >> 8, sy = (bx>>4)&15, sx = bx&15;
  const int t = threadIdx.x;
  const int bq = t>>6, l = t&63, ty = l>>2, tx = l&3;
  __shared__ __align__(16) float sP[4][2][960];   // 30,720 B
  float* const PB0 = &sP[bq][0][0];
  float* const PB1 = &sP[bq][1][0];
  for (int i=l; i<960; i+=64){ PB0[i]=0.f; PB1[i]=0.f; }  // halo stays zero
  f32x4 acc[9];
  #pragma unroll
  for (int i=0;i<9;i++) acc[i] = (f32x4){0.f,0.f,0.f,0.f};
  const float* c6 = ws + OFF_CORR6 + (size_t)bq*9*65536;
  const int wo = (2+ty)*48 + 4 + 4*tx;           // aligned b128 write offset
  #pragma unroll 1
  for (int a=0; a<5; a++){
    int Y = sy+a-2; if (Y<0 || Y>15) continue;
    #pragma unroll 1
    for (int c=0; c<5; c++){
      if (((a*5+c)&3) != g) continue;
      int X = sx+c-2; if (X<0 || X>15) continue;
      const float* pb = c6 + (size_t)(Y*16+X)*256 + l*4;
      const float* wac = k6p + (size_t)(a*5+c)*2160;   // [pr][d][48]
      float4 pf = *reinterpret_cast<const float4*>(pb);            // plane 0
      *reinterpret_cast<f32x4*>(PB0 + wo) = (f32x4){pf.x,pf.y,pf.z,pf.w};
      pf = *reinterpret_cast<const float4*>(pb + 65536);           // plane 1
      #pragma unroll
      for (int pr=0; pr<9; pr++){
        const int pi = pr/3, pj = pr%3;
        float* const cur = (pr&1) ? PB1 : PB0;
        if (pr < 8){                       // publish NEXT plane before compute
          float* nb = (pr&1) ? PB0 : PB1;
          *reinterpret_cast<f32x4*>(nb + wo) = (f32x4){pf.x,pf.y,pf.z,pf.w};
          if (pr < 7)
            pf = *reinterpret_cast<const float4*>(pb + (size_t)(pr+2)*65536);
        }
        const float* wpr = wac + pr*240;   // [d][48]
        #pragma unroll 1
        for (int d=0; d<5; d++){
          const float* rp = cur + (ty+d)*48 + 4*tx;    // aligned, conflict-free
          float4 q0 = *reinterpret_cast<const float4*>(rp);      // cols 4tx-4..
          float4 q1 = *reinterpret_cast<const float4*>(rp+4);    // cols 4tx..
          float4 q2 = *reinterpret_cast<const float4*>(rp+8);    // cols 4tx+4..
          float r12[12] = {q0.x,q0.y,q0.z,q0.w, q1.x,q1.y,q1.z,q1.w,
                           q2.x,q2.y,q2.z,q2.w};
          const float* wb = wpr + d*48;    // 45 contiguous weights (uniform)
          #pragma unroll
          for (int ki=0; ki<3; ki++){
            const int sio = pi-ki+1; if (sio<0 || sio>2) continue;
            #pragma unroll
            for (int kj=0; kj<3; kj++){
              const int sjo = pj-kj+1; if (sjo<0 || sjo>2) continue;
              const float* we = wb + (ki*3+kj)*5;
              #pragma unroll
              for (int e=0; e<5; e++)
                #pragma unroll
                for (int xi=0; xi<4; xi++)
                  acc[sio*3+sjo][xi] = fmaf(r12[e+xi+2], we[e], acc[sio*3+sjo][xi]);
            }
          }
        }
      }
    }
  }
  float* po = ws + OFF_PART + ((size_t)(g*4+bq)*9)*65536
            + (size_t)(sy*16+sx)*256 + ty*16 + tx*4;
  #pragma unroll
  for (int so=0; so<9; so++)
    *reinterpret_cast<f32x4*>(po + (size_t)so*65536) = acc[so];
}

// 7b) combine 4 parity partials + sigmoid + max over 9 so
__global__ void k_sigmax(float* __restrict__ ws){
  int id = blockIdx.x*256 + threadIdx.x;        // 4*65536
  int b = id >> 16, pos = id & 65535;
  const float* p = ws + OFF_PART + (size_t)b*589824 + pos;   // [g][b][so][pos]
  float m = -1e30f;
  #pragma unroll
  for (int so=0; so<9; so++){
    size_t o = (size_t)so*65536;
    float s = p[o] + p[o+2359296] + p[o+2u*2359296] + p[o+3u*2359296];
    m = fmaxf(m, s);
  }
  ws[OFF_MAXED + (size_t)b*65536 + pos] = 1.f/(1.f + expf(-m));
}

// ---------------------------------------------------------------------------
// 8) interpolate4d 16^4 -> 32^4
__global__ void k_interp32(float* __restrict__ ws){
  int id = blockIdx.x*256 + threadIdx.x;
  int px = id & 31, py = (id>>5)&31, ox = (id>>10)&31, oy = (id>>15)&31, b = id>>20;
  int y0,y1,x0,x1,u0,u1,v0,v1; float fy,fx,fu,fv;
  cw_coord(oy,16,32,y0,y1,fy); cw_coord(ox,16,32,x0,x1,fx);
  cw_coord(py,16,32,u0,u1,fu); cw_coord(px,16,32,v0,v1,fv);
  const float* in = ws + OFF_MAXED + (size_t)b*65536;
  int ys[2]={y0,y1}, xs[2]={x0,x1}, us[2]={u0,u1}, vs[2]={v0,v1};
  float wy[2]={1.f-fy,fy}, wx[2]={1.f-fx,fx}, wu[2]={1.f-fu,fu}, wv[2]={1.f-fv,fv};
  float s = 0.f;
  #pragma unroll
  for (int ia=0; ia<2; ia++)
    #pragma unroll
    for (int ic=0; ic<2; ic++){
      float wyx = wy[ia]*wx[ic];
      const float* base = in + ((size_t)ys[ia]*16 + xs[ic])*256;
      #pragma unroll
      for (int id_=0; id_<2; id_++)
        #pragma unroll
        for (int ie=0; ie<2; ie++)
          s += wyx*wu[id_]*wv[ie]*base[(size_t)us[id_]*16 + vs[ie]];
    }
  ws[OFF_INT32 + id] = s;
}

// ---------------------------------------------------------------------------
// 9) fast4d v3 (R7): 4 sx-outputs/block, dbuf plane staging, reg prefetch
__global__ __launch_bounds__(256) void k_fast4d(float* __restrict__ ws,
                                                const float* __restrict__ k4,
                                                const float* __restrict__ b4,
                                                float* __restrict__ out){
  const int b = blockIdx.y;
  const int sy = blockIdx.x >> 3, sx0 = (blockIdx.x & 7) << 2;
  const int t = threadIdx.x;
  const int y = t >> 3, x0 = (t & 7) << 2;
  __shared__ __align__(16) float sQ[2][36*48];
  for (int i=t; i<1728; i+=256){ sQ[0][i]=0.f; sQ[1][i]=0.f; }
  __syncthreads();
  const float* in = ws + OFF_INT32 + (size_t)b*1048576;
  float acc[4][4] = {};

  int i0 = 0;
  for (; i0 < 40; ++i0){
    int Y = sy + (i0>>3) - 2, X = sx0 - 2 + (i0&7);
    if (Y>=0 && Y<=31 && X>=0 && X<=31) break;
  }
  float4 pf = make_float4(0.f,0.f,0.f,0.f);
  if (i0 < 40){
    int Y = sy + (i0>>3) - 2, X = sx0 - 2 + (i0&7);
    pf = *reinterpret_cast<const float4*>(in + (size_t)(Y*32+X)*1024 + t*4);
  }
  int cur = 0, i = i0;
  const int srow = t >> 3, scol4 = (t & 7) << 2;
  #pragma unroll 1
  while (i < 40){
    int nx = i+1;
    for (; nx < 40; ++nx){
      int Y = sy + (nx>>3) - 2, X = sx0 - 2 + (nx&7);
      if (Y>=0 && Y<=31 && X>=0 && X<=31) break;
    }
    float* wp = &sQ[cur][(2+srow)*48 + 2 + scol4];
    wp[0]=pf.x; wp[1]=pf.y; wp[2]=pf.z; wp[3]=pf.w;
    if (nx < 40){
      int Y = sy + (nx>>3) - 2, X = sx0 - 2 + (nx&7);
      pf = *reinterpret_cast<const float4*>(in + (size_t)(Y*32+X)*1024 + t*4);
    }
    __syncthreads();
    const int a = i>>3, Xi = i&7;
    const float* ka = k4 + a*125;
    #pragma unroll
    for (int d=0; d<5; d++){
      const float* row = &sQ[cur][(y+d)*48 + x0];
      float4 q0 = *reinterpret_cast<const float4*>(row);
      float4 q1 = *reinterpret_cast<const float4*>(row+4);
      float r8[8] = {q0.x,q0.y,q0.z,q0.w,q1.x,q1.y,q1.z,q1.w};
      #pragma unroll
      for (int j=0; j<4; j++){
        const int c = Xi - j;
        if (c >= 0 && c <= 4){
          const float* kc = ka + c*25 + d*5;
          #pragma unroll
          for (int e=0; e<5; e++){
            float wv = kc[e];
            #pragma unroll
            for (int xi=0; xi<4; xi++)
              acc[j][xi] = fmaf(r8[xi+e], wv, acc[j][xi]);
          }
        }
      }
    }
    cur ^= 1; i = nx;
  }
  float bias = b4[0];
  #pragma unroll
  for (int j=0; j<4; j++){
    float4 o;
    float* po = &o.x;
    #pragma unroll
    for (int xi=0; xi<4; xi++){
      float xv = acc[j][xi] + bias;
      po[xi] = fmaxf(xv,0.f) + log1pf(expf(-fabsf(xv)));
    }
    *reinterpret_cast<float4*>(
      out + ((size_t)b*1024 + sy*32 + sx0 + j)*1024 + y*32 + x0) = o;
  }
}

// ---------------------------------------------------------------------------
// 10-12) mutual_nn_filter
__global__ void k_rowmax(const float* __restrict__ cm, float* __restrict__ ws){
  int row = blockIdx.x;
  const float* r = cm + (size_t)row*1024;
  int t = threadIdx.x;
  float m = -1e30f;
  for (int i=t; i<1024; i+=256) m = fmaxf(m, r[i]);
  __shared__ float red[256];
  red[t] = m; __syncthreads();
  for (int off=128; off; off>>=1){
    if (t < off) red[t] = fmaxf(red[t], red[t+off]);
    __syncthreads();
  }
  if (!t) ws[OFF_SMAX + row] = red[0];
}

__global__ void k_colmax_p(const float* __restrict__ cm, float* __restrict__ ws){
  int b = blockIdx.x >> 5, rg = (blockIdx.x >> 2) & 7, cg = blockIdx.x & 3;
  int c = cg*256 + threadIdx.x;
  const float* base = cm + (size_t)b*1048576 + (size_t)rg*131072 + c;
  float m = -1e30f;
  #pragma unroll 4
  for (int r=0; r<128; r++) m = fmaxf(m, base[(size_t)r*1024]);
  ws[OFF_CMAXP + (size_t)(b*8+rg)*1024 + c] = m;
}

__global__ void k_colmax_r(float* __restrict__ ws){
  int id = blockIdx.x*256 + threadIdx.x;         // 4096
  int b = id >> 10, c = id & 1023;
  float m = -1e30f;
  #pragma unroll
  for (int rg=0; rg<8; rg++)
    m = fmaxf(m, ws[OFF_CMAXP + (size_t)(b*8+rg)*1024 + c]);
  ws[OFF_TMAX + id] = m;
}

__global__ void k_mutual(float* __restrict__ cm, const float* __restrict__ ws){
  int id = blockIdx.x*256 + threadIdx.x;
  int b = id >> 20, r = (id>>10)&1023, c = id&1023;
  float v  = cm[id];
  float sm = ws[OFF_SMAX + (b<<10) + r];
  float tm = ws[OFF_TMAX + (b<<10) + c];
  sm = (sm==0.f) ? 1e-30f : sm;
  tm = (tm==0.f) ? 1e-30f : tm;
  cm[id] = v * (v/sm) * (v/tm);
}

// ---------------------------------------------------------------------------
extern "C" void kernel_launch(void* const* d_in, const int* in_sizes, int n_in,
                              void* d_out, int out_size, void* d_ws, size_t ws_size,
                              hipStream_t stream){
  const float* src = (const float*)d_in[0];
  const float* trg = (const float*)d_in[1];
  const float* w0  = (const float*)d_in[2];
  const float* w1  = (const float*)d_in[3];
  const float* w2  = (const float*)d_in[4];
  const float* k6  = (const float*)d_in[5];
  const float* k4  = (const float*)d_in[6];
  const float* b4  = (const float*)d_in[7];
  float* ws  = (float*)d_ws;    // needs WS_FLOATS*4 = ~61 MB
  float* out = (float*)d_out;
  (void)in_sizes; (void)n_in; (void)out_size; (void)ws_size;

  k_wpack       <<<3456,  256, 0, stream>>>(w0, w1, w2, ws);
  k_k6p         <<<211,   256, 0, stream>>>(k6, ws);
  k_inpack      <<<512,   256, 0, stream>>>(src, trg, ws);
  k_conv_mfma   <<<336,   256, 0, stream>>>(ws);
  k_invnorm     <<<42,    256, 0, stream>>>(ws);
  k_corr        <<<1764,  256, 0, stream>>>(ws);
  k_interp_pairs<<<9216,  256, 0, stream>>>(ws);
  k_chm6d       <<<1024,  256, 0, stream>>>(ws, ws + OFF_K6P);
  k_sigmax      <<<1024,  256, 0, stream>>>(ws);
  k_interp32    <<<16384, 256, 0, stream>>>(ws);
  k_fast4d      <<<dim3(256,4),  256, 0, stream>>>(ws, k4, b4, out);
  k_rowmax      <<<4096,  256, 0, stream>>>(out, ws);
  k_colmax_p    <<<128,   256, 0, stream>>>(out, ws);
  k_colmax_r    <<<16,    256, 0, stream>>>(ws);
  k_mutual      <<<16384, 256, 0, stream>>>(out, ws);
}

// Round 11
// 512.565 us; speedup vs baseline: 1.1888x; 1.1745x over previous
//
#include <hip/hip_runtime.h>
#include <cstdint>
#include <cstddef>

// ============================================================================
// CHMLearner forward. R11: chm6d v7 — bf16 MFMA implicit GEMM
// (C[so16][x16] += A[so][(e,pr)K] B[K][x] per (a,c,d,y-row); channels-last
// zero-padded bf16 tiles, conflict-free 48B pr-stride, fused sigmoid+max).
// Rest identical to R10.
// ============================================================================

#define DEVFN __device__ __forceinline__

typedef __attribute__((ext_vector_type(8))) short short8v;
typedef __attribute__((ext_vector_type(4))) float f32x4;
typedef unsigned int u32;
typedef unsigned short ushortv;

DEVFN void gl_lds16(const void* g, void* l){
  __builtin_amdgcn_global_load_lds(
      (const __attribute__((address_space(1))) u32*)g,
      (__attribute__((address_space(3))) u32*)l, 16, 0, 0);
}

// workspace layout (float units). Total ~61.1 MB
constexpr size_t OFF_WB    = 0;           // bf16 packed conv weights
constexpr size_t OFF_P8    = 3538944;     // bf16 padded ch-last features
constexpr size_t OFF_P16   = 3948544;
constexpr size_t OFF_P32   = 5275648;
constexpr size_t OFF_SF8   = 10010624;    // conv outputs f32 [b][256][S*S]
constexpr size_t OFF_TF8   = 10076160;
constexpr size_t OFF_SF16  = 10141696;
constexpr size_t OFF_TF16  = 10403840;
constexpr size_t OFF_SF32  = 10665984;
constexpr size_t OFF_TF32  = 11714560;
constexpr size_t OFF_INVS  = 12763136;
constexpr size_t OFF_INVT  = 12768512;
constexpr size_t OFF_SMAX  = 12773888;
constexpr size_t OFF_TMAX  = 12777984;
constexpr size_t OFF_CORR6 = 12782080;    // [4][9][16^4] f32
constexpr size_t OFF_CMAXP = OFF_CORR6 + 2359296 + 128;   // 32768 colmax partials
constexpr size_t OFF_WA    = OFF_CMAXP + 32768;           // 192,000 bf16 = 96,000 f
constexpr size_t WS_FLOATS = OFF_WA + 96128;

// aliases into dead regions (all of [0, 10,010,624) is dead post-corr):
__device__ constexpr size_t PAIR_OFF[9] = {   // raw per-pair corr [4][ss^2][ts^2]
  OFF_WB + 0,       OFF_WB + 16384,   OFF_WB + 81920,
  OFF_WB + 344064,  OFF_WB + 409600,  OFF_WB + 671744,
  OFF_WB + 1720320, OFF_WB + 1982464, OFF_WB + 3031040 };
constexpr size_t OFF_CL    = 0;            // bf16 [4][256][20][21][24] = 5,160,960 f
constexpr size_t OFF_MAXED = 9437184;      // [4][16^4] f32
constexpr size_t OFF_INT32 = 262144;       // [4][32^4] f32 (CL dead by interp32)

__device__ constexpr int SSARR[3] = {8, 16, 32};
__device__ constexpr int PAIR_START[9] = {0,4,20,84,100,164,420,484,740}; // 1764

DEVFN unsigned short f2bf(float f){
  unsigned int u = __float_as_uint(f);
  return (unsigned short)((u + 0x7fffu + ((u >> 16) & 1u)) >> 16);
}

// ---------------------------------------------------------------------------
// 1) pack conv weights into MFMA A-fragment order (bf16)
__global__ void k_wpack(const float* __restrict__ w0, const float* __restrict__ w1,
                        const float* __restrict__ w2, float* __restrict__ wsf){
  int gid = blockIdx.x*256 + threadIdx.x;        // 884,736 exact
  int scale = gid / 294912, r = gid % 294912;
  int tap = r >> 15, kc = (r>>10)&31, nc = (r>>6)&15, l = r&63;
  const float* w = (scale==0) ? w0 : (scale==1 ? w1 : w2);
  int co = nc*16 + (l&15);
  int ci0 = kc*32 + ((l>>4)&3)*8;
  unsigned short* o = (unsigned short*)(wsf + OFF_WB) + (size_t)gid*8;
  #pragma unroll
  for (int i=0;i<8;i++)
    o[i] = f2bf(w[((size_t)co*1024 + ci0 + i)*9 + tap]);
}

// 1b) pack chm6d weights into MFMA A-fragment order:
//     WA[tap=(a5+c)5+d][kc][lane][8] ; k=kc*32+8*(l>>4)+i -> (e=k>>4, pr=k&15)
__global__ void k_wa(const float* __restrict__ k6, float* __restrict__ wsf){
  int gid = blockIdx.x*256 + threadIdx.x;        // 24,000
  if (gid >= 24000) return;
  int tap = gid / 192, rem = gid % 192;
  int kc = rem / 64, l = rem % 64;
  int d = tap % 5, ac = tap / 5, a = ac / 5, c = ac % 5;
  int so = l & 15, k8 = (l >> 4) * 8;
  unsigned short* o = (unsigned short*)(wsf + OFF_WA) + (size_t)gid*8;
  #pragma unroll
  for (int i=0;i<8;i++){
    int kg = kc*32 + k8 + i;
    int e = kg >> 4, pr = kg & 15;
    float v = 0.f;
    if (so < 9 && pr < 9 && e < 5){
      int pi = pr/3, pj = pr%3, sio = so/3, sjo = so%3;
      int ki = pi - sio + 1, kj = pj - sjo + 1;
      if (ki>=0 && ki<=2 && kj>=0 && kj<=2)
        v = k6[(((((ki*3+kj)*5 + a)*5 + c)*5 + d)*5) + e];
    }
    o[i] = f2bf(v);
  }
}

// ---------------------------------------------------------------------------
// 2) inpack: stage 16 channels' 16x16 planes in LDS; emit all 3 scales
__global__ __launch_bounds__(256) void k_inpack(const float* __restrict__ src,
                                                const float* __restrict__ trg,
                                                float* __restrict__ wsf){
  int bt = blockIdx.x >> 6, cg = blockIdx.x & 63;
  int chbase = cg*16;
  int t = threadIdx.x;
  __shared__ float sIn[16][257];
  const float* gin = ((bt>=4)? trg : src) + ((size_t)(bt&3)*1024 + chbase)*256;
  #pragma unroll
  for (int i=0;i<16;i++){
    int idx = t + i*256; int ch = idx>>8, pos = idx&255;
    sIn[ch][pos] = gin[(size_t)ch*256 + pos];
  }
  __syncthreads();
  int ch = t & 15, pw = t >> 4;
  #pragma unroll 1
  for (int s=0; s<3; s++){
    int S = SSARR[s], Sp = S+2, Sp2 = Sp*Sp;
    size_t poff = (s==0)?OFF_P8 : (s==1)?OFF_P16 : OFF_P32;
    unsigned short* o = (unsigned short*)(wsf + poff) + (size_t)bt*Sp2*1024 + chbase + ch;
    float rs = 15.f/(float)(S-1);
    for (int i = pw; i < Sp2; i += 16){
      int py = i / Sp, px = i % Sp;
      float v = 0.f;
      if (py>0 && py<Sp-1 && px>0 && px<Sp-1){
        float cy = (float)(py-1)*rs, cx = (float)(px-1)*rs;
        int y0 = (int)cy; if (y0>15) y0=15; int y1 = (y0+1<16)?y0+1:15; float fy = cy-(float)y0;
        int x0 = (int)cx; if (x0>15) x0=15; int x1 = (x0+1<16)?x0+1:15; float fx = cx-(float)x0;
        v = (1.f-fy)*((1.f-fx)*sIn[ch][y0*16+x0] + fx*sIn[ch][y0*16+x1])
          +       fy*((1.f-fx)*sIn[ch][y1*16+x0] + fx*sIn[ch][y1*16+x1]);
      }
      o[(size_t)i*1024] = f2bf(v);
    }
  }
}

// ---------------------------------------------------------------------------
// 3) conv3x3 as bf16 MFMA GEMM with LDS double-buffer + global_load_lds.
__global__ __launch_bounds__(256) void k_conv_mfma(float* __restrict__ wsf){
  int bx = (blockIdx.x & 7)*42 + (blockIdx.x >> 3);   // bijective, 336 blocks
  int scale, bt, cot, post, S, lgS;
  if (bx < 256)      { scale=2; S=32; lgS=5; bt=bx>>5; cot=(bx>>4)&1; post=bx&15; }
  else if (bx < 320) { int r=bx-256; scale=1; S=16; lgS=4; bt=r>>3; cot=(r>>2)&1; post=r&3; }
  else               { int r=bx-320; scale=0; S=8;  lgS=3; bt=r>>1; cot=r&1; post=0; }
  const int Sp = S+2, N = S*S;
  const unsigned short* WbS = (const unsigned short*)(wsf + OFF_WB) + (size_t)scale*2359296;
  size_t poff = scale==0?OFF_P8: scale==1?OFF_P16:OFF_P32;
  const unsigned short* Pb = (const unsigned short*)(wsf + poff) + (size_t)bt*Sp*Sp*1024;
  size_t obase = (scale==2) ? (bt>=4?OFF_TF32:OFF_SF32)
               : (scale==1) ? (bt>=4?OFF_TF16:OFF_SF16)
                            : (bt>=4?OFF_TF8 :OFF_SF8);
  float* outp = wsf + obase + (size_t)(bt&3)*256*N;

  const int t = threadIdx.x, l = t&63, w = t>>6, wm = w&1, wn = w>>1;
  const int nc_base = cot*8;
  const int pos0 = post*64;

  __shared__ __align__(16) unsigned short Ab[2][8192];   // 32 KB
  __shared__ __align__(16) unsigned short Bb[2][4096];   // 16 KB

  f32x4 acc[4][2];
  #pragma unroll
  for (int i=0;i<4;i++)
    #pragma unroll
    for (int j=0;j<2;j++) acc[i][j] = (f32x4){0.f,0.f,0.f,0.f};

  auto STAGE = [&](int buf, int it){
    int tap = it>>4, kq = it&15;
    int dy = tap/3, dx = tap - dy*3;
    #pragma unroll
    for (int j=0;j<4;++j){
      int c = w + j*4;
      int kc = c>>3, nc = c&7;
      const unsigned short* src =
        WbS + ((((size_t)tap*32 + kq*2 + kc)*16 + nc_base + nc)*64 + l)*8;
      gl_lds16(src, &Ab[buf][c*512]);
    }
    #pragma unroll
    for (int j=0;j<2;++j){
      int c = w + j*4;
      int kc = c>>2, np = c&3;
      int pos = pos0 + np*16 + (l&15);
      int y = pos>>lgS, x = pos&(S-1);
      int row = (y+dy)*Sp + (x+dx);
      int ci = kq*64 + kc*32 + ((l>>4)<<3);
      gl_lds16(Pb + (size_t)row*1024 + ci, &Bb[buf][c*512]);
    }
  };

  STAGE(0, 0);
  __syncthreads();
  int buf = 0;
  #pragma unroll 1
  for (int it=0; it<144; ++it){
    if (it+1 < 144) STAGE(buf^1, it+1);
    #pragma unroll
    for (int kc=0; kc<2; ++kc){
      short8v a0 = *(const short8v*)&Ab[buf][((kc*8 + wm*4 + 0)*64 + l)*8];
      short8v a1 = *(const short8v*)&Ab[buf][((kc*8 + wm*4 + 1)*64 + l)*8];
      short8v a2 = *(const short8v*)&Ab[buf][((kc*8 + wm*4 + 2)*64 + l)*8];
      short8v a3 = *(const short8v*)&Ab[buf][((kc*8 + wm*4 + 3)*64 + l)*8];
      short8v b0 = *(const short8v*)&Bb[buf][((kc*4 + wn*2 + 0)*64 + l)*8];
      short8v b1 = *(const short8v*)&Bb[buf][((kc*4 + wn*2 + 1)*64 + l)*8];
      acc[0][0] = __builtin_amdgcn_mfma_f32_16x16x32_bf16(a0, b0, acc[0][0], 0,0,0);
      acc[1][0] = __builtin_amdgcn_mfma_f32_16x16x32_bf16(a1, b0, acc[1][0], 0,0,0);
      acc[2][0] = __builtin_amdgcn_mfma_f32_16x16x32_bf16(a2, b0, acc[2][0], 0,0,0);
      acc[3][0] = __builtin_amdgcn_mfma_f32_16x16x32_bf16(a3, b0, acc[3][0], 0,0,0);
      acc[0][1] = __builtin_amdgcn_mfma_f32_16x16x32_bf16(a0, b1, acc[0][1], 0,0,0);
      acc[1][1] = __builtin_amdgcn_mfma_f32_16x16x32_bf16(a1, b1, acc[1][1], 0,0,0);
      acc[2][1] = __builtin_amdgcn_mfma_f32_16x16x32_bf16(a2, b1, acc[2][1], 0,0,0);
      acc[3][1] = __builtin_amdgcn_mfma_f32_16x16x32_bf16(a3, b1, acc[3][1], 0,0,0);
    }
    __syncthreads();
    buf ^= 1;
  }

  const int r0 = (l>>4)*4, cl = l&15;
  float* ob = outp + (size_t)(cot*128 + wm*64)*N + pos0 + wn*32 + cl;
  #pragma unroll
  for (int mf=0; mf<4; ++mf)
    #pragma unroll
    for (int nf=0; nf<2; ++nf){
      float* op = ob + (size_t)(mf*16 + r0)*N + nf*16;
      #pragma unroll
      for (int i=0;i<4;++i) op[(size_t)i*N] = acc[mf][nf][i];
    }
}

// ---------------------------------------------------------------------------
// 4) inverse feature norms per position
__global__ void k_invnorm(float* __restrict__ ws){
  int id = blockIdx.x*256 + threadIdx.x;
  if (id >= 10752) return;
  int tsr = id / 5376, r = id % 5376;
  int P, q; size_t fbase;
  if (r < 256)     { P=64;   q=r;      fbase = tsr ? OFF_TF8  : OFF_SF8; }
  else if (r<1280) { P=256;  q=r-256;  fbase = tsr ? OFF_TF16 : OFF_SF16; }
  else             { P=1024; q=r-1280; fbase = tsr ? OFF_TF32 : OFF_SF32; }
  int b = q / P, pos = q % P;
  const float* f = ws + fbase + (size_t)b*256*P + pos;
  float s = 0.f;
  for (int ch=0; ch<256; ch++){ float v = f[(size_t)ch*P]; s = fmaf(v,v,s); }
  ws[(tsr ? OFF_INVT : OFF_INVS) + r] = 1.f/sqrtf(s);
}

// ---------------------------------------------------------------------------
// 5) all 9 normalized-correlation GEMMs (f32), 64x64 tiles, K=256
__global__ __launch_bounds__(256) void k_corr(float* __restrict__ ws){
  int bx = blockIdx.x;
  int p = (bx>=4)+(bx>=20)+(bx>=84)+(bx>=100)+(bx>=164)+(bx>=420)+(bx>=484)+(bx>=740);
  int si = p/3, ti = p%3;
  int M = SSARR[si]*SSARR[si], N = SSARR[ti]*SSARR[ti];
  int ntN = N >> 6;
  int rem = bx - PAIR_START[p];
  int b = rem & 3; rem >>= 2;
  int nt = rem % ntN, mt = rem / ntN;
  int m0 = mt*64, n0 = nt*64;
  const float* A  = ws + (si==0?OFF_SF8: si==1?OFF_SF16:OFF_SF32) + (size_t)b*256*M;
  const float* Bp = ws + (ti==0?OFF_TF8: ti==1?OFF_TF16:OFF_TF32) + (size_t)b*256*N;
  const float* iS = ws + OFF_INVS + (si==0?0: si==1?256:1280) + (size_t)b*M;
  const float* iT = ws + OFF_INVT + (ti==0?0: ti==1?256:1280) + (size_t)b*N;
  float* C = ws + PAIR_OFF[p] + (size_t)b*M*N;
  __shared__ __align__(16) float As[16][64];
  __shared__ __align__(16) float Bs[16][64];
  int t = threadIdx.x, tm = t>>4, tn = t&15;
  float acc[4][4] = {};
  #pragma unroll 1
  for (int k0=0; k0<256; k0+=16){
    __syncthreads();
    #pragma unroll
    for (int i=0;i<4;i++){
      int idx = t + i*256; int k = idx>>6, m = idx&63;
      As[k][m] = A [(size_t)(k0+k)*M + m0+m];
      Bs[k][m] = Bp[(size_t)(k0+k)*N + n0+m];
    }
    __syncthreads();
    #pragma unroll
    for (int k=0;k<16;k++){
      float4 av = *reinterpret_cast<const float4*>(&As[k][tm*4]);
      float4 bv = *reinterpret_cast<const float4*>(&Bs[k][tn*4]);
      float a4[4]={av.x,av.y,av.z,av.w}, b4[4]={bv.x,bv.y,bv.z,bv.w};
      #pragma unroll
      for (int i=0;i<4;i++)
        #pragma unroll
        for (int j=0;j<4;j++)
          acc[i][j] = fmaf(a4[i], b4[j], acc[i][j]);
    }
  }
  #pragma unroll
  for (int i=0;i<4;i++){
    float sv = iS[m0+tm*4+i];
    #pragma unroll
    for (int j=0;j<4;j++)
      C[(size_t)(m0+tm*4+i)*N + n0+tn*4+j] = acc[i][j]*sv*iT[n0+tn*4+j];
  }
}

// ---------------------------------------------------------------------------
DEVFN void cw_coord(int i, int n, int OH, int& i0, int& i1, float& f){
  float c = (float)(i*(n-1))/(float)(OH-1);
  int a = (int)c; if (a > n-1) a = n-1;
  i0 = a; i1 = (a+1 < n) ? a+1 : n-1; f = c - (float)a;
}

// 6) interp_pairs v2: block = (p,b,oy,ox); stage 4 corner (y,x) planes in LDS
__global__ __launch_bounds__(256) void k_interp_pairs(float* __restrict__ ws){
  int bx = blockIdx.x;
  int p = bx >> 10;
  int bl = bx & 1023;                    // [b:2][oy:4][ox:4]
  int b = bl >> 8, oy = (bl >> 4) & 15, ox = bl & 15;
  int si = p/3, ti = p%3;
  int h1 = SSARR[si], t1 = SSARR[ti], t12 = t1*t1;
  int y0,y1,x0,x1; float fy,fx;
  cw_coord(oy,h1,16,y0,y1,fy); cw_coord(ox,h1,16,x0,x1,fx);
  const float* in = ws + PAIR_OFF[p] + (size_t)b*h1*h1*t12;
  __shared__ float sPl[4][1024];
  const int t = threadIdx.x;
  {
    const float* pl0 = in + (size_t)(y0*h1+x0)*t12;
    const float* pl1 = in + (size_t)(y0*h1+x1)*t12;
    const float* pl2 = in + (size_t)(y1*h1+x0)*t12;
    const float* pl3 = in + (size_t)(y1*h1+x1)*t12;
    for (int i=t; i<t12; i+=256){
      sPl[0][i] = pl0[i]; sPl[1][i] = pl1[i];
      sPl[2][i] = pl2[i]; sPl[3][i] = pl3[i];
    }
  }
  __syncthreads();
  int px = t & 15, py = t >> 4;
  int u0,u1,v0,v1; float fu,fv;
  cw_coord(py,t1,16,u0,u1,fu); cw_coord(px,t1,16,v0,v1,fv);
  float wY[2]={1.f-fy,fy}, wX[2]={1.f-fx,fx};
  float wU[2]={1.f-fu,fu}, wV[2]={1.f-fv,fv};
  int us[2]={u0,u1}, vs[2]={v0,v1};
  float s = 0.f;
  #pragma unroll
  for (int qa=0; qa<2; qa++)
    #pragma unroll
    for (int qc=0; qc<2; qc++){
      float wyx = wY[qa]*wX[qc];
      const float* base = sPl[qa*2+qc];
      #pragma unroll
      for (int qu=0; qu<2; qu++)
        #pragma unroll
        for (int qv=0; qv<2; qv++)
          s += wyx*wU[qu]*wV[qv]*base[us[qu]*t1 + vs[qv]];
    }
  ws[OFF_CORR6 + ((size_t)b*9 + p)*65536 + ((size_t)(oy*16+ox)<<8) + t] = fmaxf(s, 0.f);
}

// ---------------------------------------------------------------------------
// 6b) channels-last bf16 zero-padded copy for chm6d MFMA:
//     CL[b][YX][y'20][x'21][pr24], value = corr6[b][pr][YX][(y'-2)*16+(x'-2)]
__global__ void k_cl(float* __restrict__ ws){
  int g = blockIdx.x*256 + threadIdx.x;          // 10,321,920 exact
  int pr = g % 24; int q = g / 24;
  int xp = q % 21; q /= 21;
  int yp = q % 20; q /= 20;
  int yx = q & 255; int b = q >> 8;
  float v = 0.f;
  if (pr < 9 && yp >= 2 && yp < 18 && xp >= 2 && xp < 18)
    v = ws[OFF_CORR6 + (((size_t)b*9 + pr) << 16) + (size_t)yx*256 + (yp-2)*16 + (xp-2)];
  ((unsigned short*)(ws + OFF_CL))[g] = f2bf(v);
}

// ---------------------------------------------------------------------------
// 7) chm6d v7: bf16 MFMA. Block = (b,sy,sx); waves own 4 y-rows each.
//    Per valid (a,c): stage CL tile (20x21x24 bf16, dbuf) via global_load_lds;
//    per row r: 3 conflict-free b128 B-frags serve all (y,d) with y+d=r;
//    A-frags from WA (L2-resident). Epilogue: max over so + sigmoid -> MAXED.
__global__ __launch_bounds__(256) void k_chm6d(float* __restrict__ ws){
  int id = (blockIdx.x & 7)*128 + (blockIdx.x >> 3);   // XCD swizzle, bijective
  const int b = id >> 8, sy = (id >> 4) & 15, sx = id & 15;
  const int t = threadIdx.x, l = t & 63, w = t >> 6;
  const int x = l & 15, h = (l >> 4) & 1, e2 = (l >> 4) >> 1;
  const unsigned short* CLu = (const unsigned short*)(ws + OFF_CL);
  const unsigned short* WAu = (const unsigned short*)(ws + OFF_WA);
  __shared__ __align__(16) unsigned short tile[2][10080];   // 40,320 B

  f32x4 acc[4];
  #pragma unroll
  for (int i=0;i<4;i++) acc[i] = (f32x4){0.f,0.f,0.f,0.f};

  auto STAGE = [&](int buf, int YX){
    const unsigned short* src = CLu + (size_t)(b*256 + YX)*10080;
    #pragma unroll
    for (int j=0;j<5;++j){
      int ch = t + j*256;
      if (ch < 1260) gl_lds16(src + (size_t)ch*8, &tile[buf][ch*8]);
    }
  };

  const int xb0 = (x + e2)*24 + 8*h;     // kc adds 48 per step

  // scan valid (a,c)
  int i0 = 0;
  for (; i0 < 25; ++i0){
    int Y = sy + i0/5 - 2, X = sx + i0%5 - 2;
    if (Y>=0 && Y<=15 && X>=0 && X<=15) break;
  }
  {
    int Y = sy + i0/5 - 2, X = sx + i0%5 - 2;
    STAGE(0, Y*16 + X);
  }
  __syncthreads();
  int buf = 0, i = i0;
  #pragma unroll 1
  while (i < 25){
    int nx = i + 1;
    for (; nx < 25; ++nx){
      int Y = sy + nx/5 - 2, X = sx + nx%5 - 2;
      if (Y>=0 && Y<=15 && X>=0 && X<=15) break;
    }
    if (nx < 25){
      int Y = sy + nx/5 - 2, X = sx + nx%5 - 2;
      STAGE(buf^1, Y*16 + X);
    }
    // compute on tile[buf] for tap (a,c) = (i/5, i%5)
    {
      const unsigned short* wa = WAu + (size_t)i*5*3*512;   // [d][kc][lane][8]
      short8v afr[5][3];
      #pragma unroll
      for (int d=0; d<5; ++d)
        #pragma unroll
        for (int kc=0; kc<3; ++kc)
          afr[d][kc] = *(const short8v*)&wa[((d*3 + kc)*64 + l)*8];
      const unsigned short* tb = &tile[buf][0];
      #pragma unroll
      for (int rl=0; rl<8; ++rl){
        const int row = (w*4 + rl)*504;
        short8v bf0 = *(const short8v*)&tb[row + xb0];
        short8v bf1 = *(const short8v*)&tb[row + xb0 + 48];
        short8v bf2 = *(const short8v*)&tb[row + xb0 + 96];
        #pragma unroll
        for (int y=0; y<4; ++y){
          if (y <= rl && rl - y <= 4){
            const int d = rl - y;
            acc[y] = __builtin_amdgcn_mfma_f32_16x16x32_bf16(afr[d][0], bf0, acc[y], 0,0,0);
            acc[y] = __builtin_amdgcn_mfma_f32_16x16x32_bf16(afr[d][1], bf1, acc[y], 0,0,0);
            acc[y] = __builtin_amdgcn_mfma_f32_16x16x32_bf16(afr[d][2], bf2, acc[y], 0,0,0);
          }
        }
      }
    }
    __syncthreads();
    buf ^= 1; i = nx;
  }

  // epilogue: max over so (rows; valid 0..8), sigmoid, write MAXED
  const int g = l >> 4;
  float* maxed = ws + OFF_MAXED + (size_t)b*65536 + (size_t)(sy*16+sx)*256;
  #pragma unroll
  for (int y=0; y<4; ++y){
    float lm;
    if (g < 2)      lm = fmaxf(fmaxf(acc[y][0], acc[y][1]), fmaxf(acc[y][2], acc[y][3]));
    else if (g==2)  lm = acc[y][0];
    else            lm = -1e30f;
    lm = fmaxf(lm, __shfl_xor(lm, 16));
    lm = fmaxf(lm, __shfl_xor(lm, 32));
    if (l < 16)
      maxed[(w*4 + y)*16 + x] = 1.f/(1.f + expf(-lm));
  }
}

// ---------------------------------------------------------------------------
// 8) interpolate4d 16^4 -> 32^4
__global__ void k_interp32(float* __restrict__ ws){
  int id = blockIdx.x*256 + threadIdx.x;
  int px = id & 31, py = (id>>5)&31, ox = (id>>10)&31, oy = (id>>15)&31, b = id>>20;
  int y0,y1,x0,x1,u0,u1,v0,v1; float fy,fx,fu,fv;
  cw_coord(oy,16,32,y0,y1,fy); cw_coord(ox,16,32,x0,x1,fx);
  cw_coord(py,16,32,u0,u1,fu); cw_coord(px,16,32,v0,v1,fv);
  const float* in = ws + OFF_MAXED + (size_t)b*65536;
  int ys[2]={y0,y1}, xs[2]={x0,x1}, us[2]={u0,u1}, vs[2]={v0,v1};
  float wy[2]={1.f-fy,fy}, wx[2]={1.f-fx,fx}, wu[2]={1.f-fu,fu}, wv[2]={1.f-fv,fv};
  float s = 0.f;
  #pragma unroll
  for (int ia=0; ia<2; ia++)
    #pragma unroll
    for (int ic=0; ic<2; ic++){
      float wyx = wy[ia]*wx[ic];
      const float* base = in + ((size_t)ys[ia]*16 + xs[ic])*256;
      #pragma unroll
      for (int id_=0; id_<2; id_++)
        #pragma unroll
        for (int ie=0; ie<2; ie++)
          s += wyx*wu[id_]*wv[ie]*base[(size_t)us[id_]*16 + vs[ie]];
    }
  ws[OFF_INT32 + id] = s;
}

// ---------------------------------------------------------------------------
// 9) fast4d v3 (R7): 4 sx-outputs/block, dbuf plane staging, reg prefetch
__global__ __launch_bounds__(256) void k_fast4d(float* __restrict__ ws,
                                                const float* __restrict__ k4,
                                                const float* __restrict__ b4,
                                                float* __restrict__ out){
  const int b = blockIdx.y;
  const int sy = blockIdx.x >> 3, sx0 = (blockIdx.x & 7) << 2;
  const int t = threadIdx.x;
  const int y = t >> 3, x0 = (t & 7) << 2;
  __shared__ __align__(16) float sQ[2][36*48];
  for (int i=t; i<1728; i+=256){ sQ[0][i]=0.f; sQ[1][i]=0.f; }
  __syncthreads();
  const float* in = ws + OFF_INT32 + (size_t)b*1048576;
  float acc[4][4] = {};

  int i0 = 0;
  for (; i0 < 40; ++i0){
    int Y = sy + (i0>>3) - 2, X = sx0 - 2 + (i0&7);
    if (Y>=0 && Y<=31 && X>=0 && X<=31) break;
  }
  float4 pf = make_float4(0.f,0.f,0.f,0.f);
  if (i0 < 40){
    int Y = sy + (i0>>3) - 2, X = sx0 - 2 + (i0&7);
    pf = *reinterpret_cast<const float4*>(in + (size_t)(Y*32+X)*1024 + t*4);
  }
  int cur = 0, i = i0;
  const int srow = t >> 3, scol4 = (t & 7) << 2;
  #pragma unroll 1
  while (i < 40){
    int nx = i+1;
    for (; nx < 40; ++nx){
      int Y = sy + (nx>>3) - 2, X = sx0 - 2 + (nx&7);
      if (Y>=0 && Y<=31 && X>=0 && X<=31) break;
    }
    float* wp = &sQ[cur][(2+srow)*48 + 2 + scol4];
    wp[0]=pf.x; wp[1]=pf.y; wp[2]=pf.z; wp[3]=pf.w;
    if (nx < 40){
      int Y = sy + (nx>>3) - 2, X = sx0 - 2 + (nx&7);
      pf = *reinterpret_cast<const float4*>(in + (size_t)(Y*32+X)*1024 + t*4);
    }
    __syncthreads();
    const int a = i>>3, Xi = i&7;
    const float* ka = k4 + a*125;
    #pragma unroll
    for (int d=0; d<5; d++){
      const float* row = &sQ[cur][(y+d)*48 + x0];
      float4 q0 = *reinterpret_cast<const float4*>(row);
      float4 q1 = *reinterpret_cast<const float4*>(row+4);
      float r8[8] = {q0.x,q0.y,q0.z,q0.w,q1.x,q1.y,q1.z,q1.w};
      #pragma unroll
      for (int j=0; j<4; j++){
        const int c = Xi - j;
        if (c >= 0 && c <= 4){
          const float* kc = ka + c*25 + d*5;
          #pragma unroll
          for (int e=0; e<5; e++){
            float wv = kc[e];
            #pragma unroll
            for (int xi=0; xi<4; xi++)
              acc[j][xi] = fmaf(r8[xi+e], wv, acc[j][xi]);
          }
        }
      }
    }
    cur ^= 1; i = nx;
  }
  float bias = b4[0];
  #pragma unroll
  for (int j=0; j<4; j++){
    float4 o;
    float* po = &o.x;
    #pragma unroll
    for (int xi=0; xi<4; xi++){
      float xv = acc[j][xi] + bias;
      po[xi] = fmaxf(xv,0.f) + log1pf(expf(-fabsf(xv)));
    }
    *reinterpret_cast<float4*>(
      out + ((size_t)b*1024 + sy*32 + sx0 + j)*1024 + y*32 + x0) = o;
  }
}

// ---------------------------------------------------------------------------
// 10-12) mutual_nn_filter
__global__ void k_rowmax(const float* __restrict__ cm, float* __restrict__ ws){
  int row = blockIdx.x;
  const float* r = cm + (size_t)row*1024;
  int t = threadIdx.x;
  float m = -1e30f;
  for (int i=t; i<1024; i+=256) m = fmaxf(m, r[i]);
  __shared__ float red[256];
  red[t] = m; __syncthreads();
  for (int off=128; off; off>>=1){
    if (t < off) red[t] = fmaxf(red[t], red[t+off]);
    __syncthreads();
  }
  if (!t) ws[OFF_SMAX + row] = red[0];
}

__global__ void k_colmax_p(const float* __restrict__ cm, float* __restrict__ ws){
  int b = blockIdx.x >> 5, rg = (blockIdx.x >> 2) & 7, cg = blockIdx.x & 3;
  int c = cg*256 + threadIdx.x;
  const float* base = cm + (size_t)b*1048576 + (size_t)rg*131072 + c;
  float m = -1e30f;
  #pragma unroll 4
  for (int r=0; r<128; r++) m = fmaxf(m, base[(size_t)r*1024]);
  ws[OFF_CMAXP + (size_t)(b*8+rg)*1024 + c] = m;
}

__global__ void k_colmax_r(float* __restrict__ ws){
  int id = blockIdx.x*256 + threadIdx.x;         // 4096
  int b = id >> 10, c = id & 1023;
  float m = -1e30f;
  #pragma unroll
  for (int rg=0; rg<8; rg++)
    m = fmaxf(m, ws[OFF_CMAXP + (size_t)(b*8+rg)*1024 + c]);
  ws[OFF_TMAX + id] = m;
}

__global__ void k_mutual(float* __restrict__ cm, const float* __restrict__ ws){
  int id = blockIdx.x*256 + threadIdx.x;
  int b = id >> 20, r = (id>>10)&1023, c = id&1023;
  float v  = cm[id];
  float sm = ws[OFF_SMAX + (b<<10) + r];
  float tm = ws[OFF_TMAX + (b<<10) + c];
  sm = (sm==0.f) ? 1e-30f : sm;
  tm = (tm==0.f) ? 1e-30f : tm;
  cm[id] = v * (v/sm) * (v/tm);
}

// ---------------------------------------------------------------------------
extern "C" void kernel_launch(void* const* d_in, const int* in_sizes, int n_in,
                              void* d_out, int out_size, void* d_ws, size_t ws_size,
                              hipStream_t stream){
  const float* src = (const float*)d_in[0];
  const float* trg = (const float*)d_in[1];
  const float* w0  = (const float*)d_in[2];
  const float* w1  = (const float*)d_in[3];
  const float* w2  = (const float*)d_in[4];
  const float* k6  = (const float*)d_in[5];
  const float* k4  = (const float*)d_in[6];
  const float* b4  = (const float*)d_in[7];
  float* ws  = (float*)d_ws;    // needs WS_FLOATS*4 = ~61.1 MB
  float* out = (float*)d_out;
  (void)in_sizes; (void)n_in; (void)out_size; (void)ws_size;

  k_wpack       <<<3456,  256, 0, stream>>>(w0, w1, w2, ws);
  k_wa          <<<94,    256, 0, stream>>>(k6, ws);
  k_inpack      <<<512,   256, 0, stream>>>(src, trg, ws);
  k_conv_mfma   <<<336,   256, 0, stream>>>(ws);
  k_invnorm     <<<42,    256, 0, stream>>>(ws);
  k_corr        <<<1764,  256, 0, stream>>>(ws);
  k_interp_pairs<<<9216,  256, 0, stream>>>(ws);
  k_cl          <<<40320, 256, 0, stream>>>(ws);
  k_chm6d       <<<1024,  256, 0, stream>>>(ws);
  k_interp32    <<<16384, 256, 0, stream>>>(ws);
  k_fast4d      <<<dim3(256,4),  256, 0, stream>>>(ws, k4, b4, out);
  k_rowmax      <<<4096,  256, 0, stream>>>(out, ws);
  k_colmax_p    <<<128,   256, 0, stream>>>(out, ws);
  k_colmax_r    <<<16,    256, 0, stream>>>(ws);
  k_mutual      <<<16384, 256, 0, stream>>>(out, ws);
}

// Round 12
// 472.323 us; speedup vs baseline: 1.2901x; 1.0852x over previous
//
#include <hip/hip_runtime.h>
#include <cstdint>
#include <cstddef>

// ============================================================================
// CHMLearner forward. R12: conv K-split x2 (672 blocks, ks=1 -> partial buffer,
// tiny combine kernel) to fix grid starvation (336 blocks / 256 CUs).
// chm6d v7 MFMA (R11) and rest unchanged.
// ============================================================================

#define DEVFN __device__ __forceinline__

typedef __attribute__((ext_vector_type(8))) short short8v;
typedef __attribute__((ext_vector_type(4))) float f32x4;
typedef unsigned int u32;

DEVFN void gl_lds16(const void* g, void* l){
  __builtin_amdgcn_global_load_lds(
      (const __attribute__((address_space(1))) u32*)g,
      (__attribute__((address_space(3))) u32*)l, 16, 0, 0);
}

// workspace layout (float units). Total ~72.1 MB
constexpr size_t OFF_WB    = 0;           // bf16 packed conv weights
constexpr size_t OFF_P8    = 3538944;     // bf16 padded ch-last features
constexpr size_t OFF_P16   = 3948544;
constexpr size_t OFF_P32   = 5275648;
constexpr size_t OFF_SF8   = 10010624;    // conv outputs f32 [b][256][S*S]
constexpr size_t OFF_TF8   = 10076160;
constexpr size_t OFF_SF16  = 10141696;
constexpr size_t OFF_TF16  = 10403840;
constexpr size_t OFF_SF32  = 10665984;
constexpr size_t OFF_TF32  = 11714560;
constexpr size_t OFF_INVS  = 12763136;
constexpr size_t OFF_INVT  = 12768512;
constexpr size_t OFF_SMAX  = 12773888;
constexpr size_t OFF_TMAX  = 12777984;
constexpr size_t OFF_CORR6 = 12782080;    // [4][9][16^4] f32
constexpr size_t OFF_CMAXP = OFF_CORR6 + 2359296 + 128;   // 32768 colmax partials
constexpr size_t OFF_WA    = OFF_CMAXP + 32768;           // 192,000 bf16
constexpr size_t OFF_PARTK = OFF_WA + 96128;              // 2,752,512 conv K-partials
constexpr size_t WS_FLOATS = OFF_PARTK + 2752512;

// aliases into dead regions (all of [0, 10,010,624) is dead post-corr):
__device__ constexpr size_t PAIR_OFF[9] = {   // raw per-pair corr [4][ss^2][ts^2]
  OFF_WB + 0,       OFF_WB + 16384,   OFF_WB + 81920,
  OFF_WB + 344064,  OFF_WB + 409600,  OFF_WB + 671744,
  OFF_WB + 1720320, OFF_WB + 1982464, OFF_WB + 3031040 };
constexpr size_t OFF_CL    = 0;            // bf16 [4][256][20][21][24]
constexpr size_t OFF_MAXED = 9437184;      // [4][16^4] f32
constexpr size_t OFF_INT32 = 262144;       // [4][32^4] f32 (CL dead by interp32)

__device__ constexpr int SSARR[3] = {8, 16, 32};
__device__ constexpr int PAIR_START[9] = {0,4,20,84,100,164,420,484,740}; // 1764

DEVFN unsigned short f2bf(float f){
  unsigned int u = __float_as_uint(f);
  return (unsigned short)((u + 0x7fffu + ((u >> 16) & 1u)) >> 16);
}

// ---------------------------------------------------------------------------
// 1) pack conv weights into MFMA A-fragment order (bf16)
__global__ void k_wpack(const float* __restrict__ w0, const float* __restrict__ w1,
                        const float* __restrict__ w2, float* __restrict__ wsf){
  int gid = blockIdx.x*256 + threadIdx.x;        // 884,736 exact
  int scale = gid / 294912, r = gid % 294912;
  int tap = r >> 15, kc = (r>>10)&31, nc = (r>>6)&15, l = r&63;
  const float* w = (scale==0) ? w0 : (scale==1 ? w1 : w2);
  int co = nc*16 + (l&15);
  int ci0 = kc*32 + ((l>>4)&3)*8;
  unsigned short* o = (unsigned short*)(wsf + OFF_WB) + (size_t)gid*8;
  #pragma unroll
  for (int i=0;i<8;i++)
    o[i] = f2bf(w[((size_t)co*1024 + ci0 + i)*9 + tap]);
}

// 1b) pack chm6d weights into MFMA A-fragment order
__global__ void k_wa(const float* __restrict__ k6, float* __restrict__ wsf){
  int gid = blockIdx.x*256 + threadIdx.x;        // 24,000
  if (gid >= 24000) return;
  int tap = gid / 192, rem = gid % 192;
  int kc = rem / 64, l = rem % 64;
  int d = tap % 5, ac = tap / 5, a = ac / 5, c = ac % 5;
  int so = l & 15, k8 = (l >> 4) * 8;
  unsigned short* o = (unsigned short*)(wsf + OFF_WA) + (size_t)gid*8;
  #pragma unroll
  for (int i=0;i<8;i++){
    int kg = kc*32 + k8 + i;
    int e = kg >> 4, pr = kg & 15;
    float v = 0.f;
    if (so < 9 && pr < 9 && e < 5){
      int pi = pr/3, pj = pr%3, sio = so/3, sjo = so%3;
      int ki = pi - sio + 1, kj = pj - sjo + 1;
      if (ki>=0 && ki<=2 && kj>=0 && kj<=2)
        v = k6[(((((ki*3+kj)*5 + a)*5 + c)*5 + d)*5) + e];
    }
    o[i] = f2bf(v);
  }
}

// ---------------------------------------------------------------------------
// 2) inpack: stage 16 channels' 16x16 planes in LDS; emit all 3 scales
__global__ __launch_bounds__(256) void k_inpack(const float* __restrict__ src,
                                                const float* __restrict__ trg,
                                                float* __restrict__ wsf){
  int bt = blockIdx.x >> 6, cg = blockIdx.x & 63;
  int chbase = cg*16;
  int t = threadIdx.x;
  __shared__ float sIn[16][257];
  const float* gin = ((bt>=4)? trg : src) + ((size_t)(bt&3)*1024 + chbase)*256;
  #pragma unroll
  for (int i=0;i<16;i++){
    int idx = t + i*256; int ch = idx>>8, pos = idx&255;
    sIn[ch][pos] = gin[(size_t)ch*256 + pos];
  }
  __syncthreads();
  int ch = t & 15, pw = t >> 4;
  #pragma unroll 1
  for (int s=0; s<3; s++){
    int S = SSARR[s], Sp = S+2, Sp2 = Sp*Sp;
    size_t poff = (s==0)?OFF_P8 : (s==1)?OFF_P16 : OFF_P32;
    unsigned short* o = (unsigned short*)(wsf + poff) + (size_t)bt*Sp2*1024 + chbase + ch;
    float rs = 15.f/(float)(S-1);
    for (int i = pw; i < Sp2; i += 16){
      int py = i / Sp, px = i % Sp;
      float v = 0.f;
      if (py>0 && py<Sp-1 && px>0 && px<Sp-1){
        float cy = (float)(py-1)*rs, cx = (float)(px-1)*rs;
        int y0 = (int)cy; if (y0>15) y0=15; int y1 = (y0+1<16)?y0+1:15; float fy = cy-(float)y0;
        int x0 = (int)cx; if (x0>15) x0=15; int x1 = (x0+1<16)?x0+1:15; float fx = cx-(float)x0;
        v = (1.f-fy)*((1.f-fx)*sIn[ch][y0*16+x0] + fx*sIn[ch][y0*16+x1])
          +       fy*((1.f-fx)*sIn[ch][y1*16+x0] + fx*sIn[ch][y1*16+x1]);
      }
      o[(size_t)i*1024] = f2bf(v);
    }
  }
}

// ---------------------------------------------------------------------------
// 3) conv3x3 bf16 MFMA GEMM, K-split x2. 672 blocks; ks=0 -> outputs,
//    ks=1 -> PARTK partials (same internal layout). k_combine sums.
__global__ __launch_bounds__(256) void k_conv_mfma(float* __restrict__ wsf){
  int bs = (blockIdx.x & 7)*84 + (blockIdx.x >> 3);   // bijective, 672 blocks
  const int ks = bs & 1;
  int bx = bs >> 1;
  int scale, bt, cot, post, S, lgS;
  if (bx < 256)      { scale=2; S=32; lgS=5; bt=bx>>5; cot=(bx>>4)&1; post=bx&15; }
  else if (bx < 320) { int r=bx-256; scale=1; S=16; lgS=4; bt=r>>3; cot=(r>>2)&1; post=r&3; }
  else               { int r=bx-320; scale=0; S=8;  lgS=3; bt=r>>1; cot=r&1; post=0; }
  const int Sp = S+2, N = S*S;
  const unsigned short* WbS = (const unsigned short*)(wsf + OFF_WB) + (size_t)scale*2359296;
  size_t poff = scale==0?OFF_P8: scale==1?OFF_P16:OFF_P32;
  const unsigned short* Pb = (const unsigned short*)(wsf + poff) + (size_t)bt*Sp*Sp*1024;
  size_t obase = (scale==2) ? (bt>=4?OFF_TF32:OFF_SF32)
               : (scale==1) ? (bt>=4?OFF_TF16:OFF_SF16)
                            : (bt>=4?OFF_TF8 :OFF_SF8);
  if (ks) obase += OFF_PARTK - OFF_SF8;
  float* outp = wsf + obase + (size_t)(bt&3)*256*N;

  const int t = threadIdx.x, l = t&63, w = t>>6, wm = w&1, wn = w>>1;
  const int nc_base = cot*8;
  const int pos0 = post*64;
  const int it0 = ks*72, it1 = it0 + 72;

  __shared__ __align__(16) unsigned short Ab[2][8192];   // 32 KB
  __shared__ __align__(16) unsigned short Bb[2][4096];   // 16 KB

  f32x4 acc[4][2];
  #pragma unroll
  for (int i=0;i<4;i++)
    #pragma unroll
    for (int j=0;j<2;j++) acc[i][j] = (f32x4){0.f,0.f,0.f,0.f};

  auto STAGE = [&](int buf, int it){
    int tap = it>>4, kq = it&15;
    int dy = tap/3, dx = tap - dy*3;
    #pragma unroll
    for (int j=0;j<4;++j){
      int c = w + j*4;
      int kc = c>>3, nc = c&7;
      const unsigned short* src =
        WbS + ((((size_t)tap*32 + kq*2 + kc)*16 + nc_base + nc)*64 + l)*8;
      gl_lds16(src, &Ab[buf][c*512]);
    }
    #pragma unroll
    for (int j=0;j<2;++j){
      int c = w + j*4;
      int kc = c>>2, np = c&3;
      int pos = pos0 + np*16 + (l&15);
      int y = pos>>lgS, x = pos&(S-1);
      int row = (y+dy)*Sp + (x+dx);
      int ci = kq*64 + kc*32 + ((l>>4)<<3);
      gl_lds16(Pb + (size_t)row*1024 + ci, &Bb[buf][c*512]);
    }
  };

  STAGE(0, it0);
  __syncthreads();
  int buf = 0;
  #pragma unroll 1
  for (int it=it0; it<it1; ++it){
    if (it+1 < it1) STAGE(buf^1, it+1);
    #pragma unroll
    for (int kc=0; kc<2; ++kc){
      short8v a0 = *(const short8v*)&Ab[buf][((kc*8 + wm*4 + 0)*64 + l)*8];
      short8v a1 = *(const short8v*)&Ab[buf][((kc*8 + wm*4 + 1)*64 + l)*8];
      short8v a2 = *(const short8v*)&Ab[buf][((kc*8 + wm*4 + 2)*64 + l)*8];
      short8v a3 = *(const short8v*)&Ab[buf][((kc*8 + wm*4 + 3)*64 + l)*8];
      short8v b0 = *(const short8v*)&Bb[buf][((kc*4 + wn*2 + 0)*64 + l)*8];
      short8v b1 = *(const short8v*)&Bb[buf][((kc*4 + wn*2 + 1)*64 + l)*8];
      acc[0][0] = __builtin_amdgcn_mfma_f32_16x16x32_bf16(a0, b0, acc[0][0], 0,0,0);
      acc[1][0] = __builtin_amdgcn_mfma_f32_16x16x32_bf16(a1, b0, acc[1][0], 0,0,0);
      acc[2][0] = __builtin_amdgcn_mfma_f32_16x16x32_bf16(a2, b0, acc[2][0], 0,0,0);
      acc[3][0] = __builtin_amdgcn_mfma_f32_16x16x32_bf16(a3, b0, acc[3][0], 0,0,0);
      acc[0][1] = __builtin_amdgcn_mfma_f32_16x16x32_bf16(a0, b1, acc[0][1], 0,0,0);
      acc[1][1] = __builtin_amdgcn_mfma_f32_16x16x32_bf16(a1, b1, acc[1][1], 0,0,0);
      acc[2][1] = __builtin_amdgcn_mfma_f32_16x16x32_bf16(a2, b1, acc[2][1], 0,0,0);
      acc[3][1] = __builtin_amdgcn_mfma_f32_16x16x32_bf16(a3, b1, acc[3][1], 0,0,0);
    }
    __syncthreads();
    buf ^= 1;
  }

  const int r0 = (l>>4)*4, cl = l&15;
  float* ob = outp + (size_t)(cot*128 + wm*64)*N + pos0 + wn*32 + cl;
  #pragma unroll
  for (int mf=0; mf<4; ++mf)
    #pragma unroll
    for (int nf=0; nf<2; ++nf){
      float* op = ob + (size_t)(mf*16 + r0)*N + nf*16;
      #pragma unroll
      for (int i=0;i<4;++i) op[(size_t)i*N] = acc[mf][nf][i];
    }
}

// 3b) combine conv K-partials: outputs += PARTK
__global__ void k_combine(float* __restrict__ ws){
  int i = blockIdx.x*256 + threadIdx.x;          // 2,752,512 exact
  ws[OFF_SF8 + i] += ws[OFF_PARTK + i];
}

// ---------------------------------------------------------------------------
// 4) inverse feature norms per position
__global__ void k_invnorm(float* __restrict__ ws){
  int id = blockIdx.x*256 + threadIdx.x;
  if (id >= 10752) return;
  int tsr = id / 5376, r = id % 5376;
  int P, q; size_t fbase;
  if (r < 256)     { P=64;   q=r;      fbase = tsr ? OFF_TF8  : OFF_SF8; }
  else if (r<1280) { P=256;  q=r-256;  fbase = tsr ? OFF_TF16 : OFF_SF16; }
  else             { P=1024; q=r-1280; fbase = tsr ? OFF_TF32 : OFF_SF32; }
  int b = q / P, pos = q % P;
  const float* f = ws + fbase + (size_t)b*256*P + pos;
  float s = 0.f;
  for (int ch=0; ch<256; ch++){ float v = f[(size_t)ch*P]; s = fmaf(v,v,s); }
  ws[(tsr ? OFF_INVT : OFF_INVS) + r] = 1.f/sqrtf(s);
}

// ---------------------------------------------------------------------------
// 5) all 9 normalized-correlation GEMMs (f32), 64x64 tiles, K=256
__global__ __launch_bounds__(256) void k_corr(float* __restrict__ ws){
  int bx = blockIdx.x;
  int p = (bx>=4)+(bx>=20)+(bx>=84)+(bx>=100)+(bx>=164)+(bx>=420)+(bx>=484)+(bx>=740);
  int si = p/3, ti = p%3;
  int M = SSARR[si]*SSARR[si], N = SSARR[ti]*SSARR[ti];
  int ntN = N >> 6;
  int rem = bx - PAIR_START[p];
  int b = rem & 3; rem >>= 2;
  int nt = rem % ntN, mt = rem / ntN;
  int m0 = mt*64, n0 = nt*64;
  const float* A  = ws + (si==0?OFF_SF8: si==1?OFF_SF16:OFF_SF32) + (size_t)b*256*M;
  const float* Bp = ws + (ti==0?OFF_TF8: ti==1?OFF_TF16:OFF_TF32) + (size_t)b*256*N;
  const float* iS = ws + OFF_INVS + (si==0?0: si==1?256:1280) + (size_t)b*M;
  const float* iT = ws + OFF_INVT + (ti==0?0: ti==1?256:1280) + (size_t)b*N;
  float* C = ws + PAIR_OFF[p] + (size_t)b*M*N;
  __shared__ __align__(16) float As[16][64];
  __shared__ __align__(16) float Bs[16][64];
  int t = threadIdx.x, tm = t>>4, tn = t&15;
  float acc[4][4] = {};
  #pragma unroll 1
  for (int k0=0; k0<256; k0+=16){
    __syncthreads();
    #pragma unroll
    for (int i=0;i<4;i++){
      int idx = t + i*256; int k = idx>>6, m = idx&63;
      As[k][m] = A [(size_t)(k0+k)*M + m0+m];
      Bs[k][m] = Bp[(size_t)(k0+k)*N + n0+m];
    }
    __syncthreads();
    #pragma unroll
    for (int k=0;k<16;k++){
      float4 av = *reinterpret_cast<const float4*>(&As[k][tm*4]);
      float4 bv = *reinterpret_cast<const float4*>(&Bs[k][tn*4]);
      float a4[4]={av.x,av.y,av.z,av.w}, b4[4]={bv.x,bv.y,bv.z,bv.w};
      #pragma unroll
      for (int i=0;i<4;i++)
        #pragma unroll
        for (int j=0;j<4;j++)
          acc[i][j] = fmaf(a4[i], b4[j], acc[i][j]);
    }
  }
  #pragma unroll
  for (int i=0;i<4;i++){
    float sv = iS[m0+tm*4+i];
    #pragma unroll
    for (int j=0;j<4;j++)
      C[(size_t)(m0+tm*4+i)*N + n0+tn*4+j] = acc[i][j]*sv*iT[n0+tn*4+j];
  }
}

// ---------------------------------------------------------------------------
DEVFN void cw_coord(int i, int n, int OH, int& i0, int& i1, float& f){
  float c = (float)(i*(n-1))/(float)(OH-1);
  int a = (int)c; if (a > n-1) a = n-1;
  i0 = a; i1 = (a+1 < n) ? a+1 : n-1; f = c - (float)a;
}

// 6) interp_pairs v2: block = (p,b,oy,ox); stage 4 corner (y,x) planes in LDS
__global__ __launch_bounds__(256) void k_interp_pairs(float* __restrict__ ws){
  int bx = blockIdx.x;
  int p = bx >> 10;
  int bl = bx & 1023;                    // [b:2][oy:4][ox:4]
  int b = bl >> 8, oy = (bl >> 4) & 15, ox = bl & 15;
  int si = p/3, ti = p%3;
  int h1 = SSARR[si], t1 = SSARR[ti], t12 = t1*t1;
  int y0,y1,x0,x1; float fy,fx;
  cw_coord(oy,h1,16,y0,y1,fy); cw_coord(ox,h1,16,x0,x1,fx);
  const float* in = ws + PAIR_OFF[p] + (size_t)b*h1*h1*t12;
  __shared__ float sPl[4][1024];
  const int t = threadIdx.x;
  {
    const float* pl0 = in + (size_t)(y0*h1+x0)*t12;
    const float* pl1 = in + (size_t)(y0*h1+x1)*t12;
    const float* pl2 = in + (size_t)(y1*h1+x0)*t12;
    const float* pl3 = in + (size_t)(y1*h1+x1)*t12;
    for (int i=t; i<t12; i+=256){
      sPl[0][i] = pl0[i]; sPl[1][i] = pl1[i];
      sPl[2][i] = pl2[i]; sPl[3][i] = pl3[i];
    }
  }
  __syncthreads();
  int px = t & 15, py = t >> 4;
  int u0,u1,v0,v1; float fu,fv;
  cw_coord(py,t1,16,u0,u1,fu); cw_coord(px,t1,16,v0,v1,fv);
  float wY[2]={1.f-fy,fy}, wX[2]={1.f-fx,fx};
  float wU[2]={1.f-fu,fu}, wV[2]={1.f-fv,fv};
  int us[2]={u0,u1}, vs[2]={v0,v1};
  float s = 0.f;
  #pragma unroll
  for (int qa=0; qa<2; qa++)
    #pragma unroll
    for (int qc=0; qc<2; qc++){
      float wyx = wY[qa]*wX[qc];
      const float* base = sPl[qa*2+qc];
      #pragma unroll
      for (int qu=0; qu<2; qu++)
        #pragma unroll
        for (int qv=0; qv<2; qv++)
          s += wyx*wU[qu]*wV[qv]*base[us[qu]*t1 + vs[qv]];
    }
  ws[OFF_CORR6 + ((size_t)b*9 + p)*65536 + ((size_t)(oy*16+ox)<<8) + t] = fmaxf(s, 0.f);
}

// ---------------------------------------------------------------------------
// 6b) channels-last bf16 zero-padded copy for chm6d MFMA
__global__ void k_cl(float* __restrict__ ws){
  int g = blockIdx.x*256 + threadIdx.x;          // 10,321,920 exact
  int pr = g % 24; int q = g / 24;
  int xp = q % 21; q /= 21;
  int yp = q % 20; q /= 20;
  int yx = q & 255; int b = q >> 8;
  float v = 0.f;
  if (pr < 9 && yp >= 2 && yp < 18 && xp >= 2 && xp < 18)
    v = ws[OFF_CORR6 + (((size_t)b*9 + pr) << 16) + (size_t)yx*256 + (yp-2)*16 + (xp-2)];
  ((unsigned short*)(ws + OFF_CL))[g] = f2bf(v);
}

// ---------------------------------------------------------------------------
// 7) chm6d v7: bf16 MFMA implicit GEMM + fused sigmoid/max epilogue
__global__ __launch_bounds__(256) void k_chm6d(float* __restrict__ ws){
  int id = (blockIdx.x & 7)*128 + (blockIdx.x >> 3);   // XCD swizzle, bijective
  const int b = id >> 8, sy = (id >> 4) & 15, sx = id & 15;
  const int t = threadIdx.x, l = t & 63, w = t >> 6;
  const int x = l & 15, h = (l >> 4) & 1, e2 = (l >> 4) >> 1;
  const unsigned short* CLu = (const unsigned short*)(ws + OFF_CL);
  const unsigned short* WAu = (const unsigned short*)(ws + OFF_WA);
  __shared__ __align__(16) unsigned short tile[2][10080];   // 40,320 B

  f32x4 acc[4];
  #pragma unroll
  for (int i=0;i<4;i++) acc[i] = (f32x4){0.f,0.f,0.f,0.f};

  auto STAGE = [&](int buf, int YX){
    const unsigned short* src = CLu + (size_t)(b*256 + YX)*10080;
    #pragma unroll
    for (int j=0;j<5;++j){
      int ch = t + j*256;
      if (ch < 1260) gl_lds16(src + (size_t)ch*8, &tile[buf][ch*8]);
    }
  };

  const int xb0 = (x + e2)*24 + 8*h;

  int i0 = 0;
  for (; i0 < 25; ++i0){
    int Y = sy + i0/5 - 2, X = sx + i0%5 - 2;
    if (Y>=0 && Y<=15 && X>=0 && X<=15) break;
  }
  {
    int Y = sy + i0/5 - 2, X = sx + i0%5 - 2;
    STAGE(0, Y*16 + X);
  }
  __syncthreads();
  int buf = 0, i = i0;
  #pragma unroll 1
  while (i < 25){
    int nx = i + 1;
    for (; nx < 25; ++nx){
      int Y = sy + nx/5 - 2, X = sx + nx%5 - 2;
      if (Y>=0 && Y<=15 && X>=0 && X<=15) break;
    }
    if (nx < 25){
      int Y = sy + nx/5 - 2, X = sx + nx%5 - 2;
      STAGE(buf^1, Y*16 + X);
    }
    {
      const unsigned short* wa = WAu + (size_t)i*5*3*512;   // [d][kc][lane][8]
      short8v afr[5][3];
      #pragma unroll
      for (int d=0; d<5; ++d)
        #pragma unroll
        for (int kc=0; kc<3; ++kc)
          afr[d][kc] = *(const short8v*)&wa[((d*3 + kc)*64 + l)*8];
      const unsigned short* tb = &tile[buf][0];
      #pragma unroll
      for (int rl=0; rl<8; ++rl){
        const int row = (w*4 + rl)*504;
        short8v bf0 = *(const short8v*)&tb[row + xb0];
        short8v bf1 = *(const short8v*)&tb[row + xb0 + 48];
        short8v bf2 = *(const short8v*)&tb[row + xb0 + 96];
        #pragma unroll
        for (int y=0; y<4; ++y){
          if (y <= rl && rl - y <= 4){
            const int d = rl - y;
            acc[y] = __builtin_amdgcn_mfma_f32_16x16x32_bf16(afr[d][0], bf0, acc[y], 0,0,0);
            acc[y] = __builtin_amdgcn_mfma_f32_16x16x32_bf16(afr[d][1], bf1, acc[y], 0,0,0);
            acc[y] = __builtin_amdgcn_mfma_f32_16x16x32_bf16(afr[d][2], bf2, acc[y], 0,0,0);
          }
        }
      }
    }
    __syncthreads();
    buf ^= 1; i = nx;
  }

  const int g = l >> 4;
  float* maxed = ws + OFF_MAXED + (size_t)b*65536 + (size_t)(sy*16+sx)*256;
  #pragma unroll
  for (int y=0; y<4; ++y){
    float lm;
    if (g < 2)      lm = fmaxf(fmaxf(acc[y][0], acc[y][1]), fmaxf(acc[y][2], acc[y][3]));
    else if (g==2)  lm = acc[y][0];
    else            lm = -1e30f;
    lm = fmaxf(lm, __shfl_xor(lm, 16));
    lm = fmaxf(lm, __shfl_xor(lm, 32));
    if (l < 16)
      maxed[(w*4 + y)*16 + x] = 1.f/(1.f + expf(-lm));
  }
}

// ---------------------------------------------------------------------------
// 8) interpolate4d 16^4 -> 32^4
__global__ void k_interp32(float* __restrict__ ws){
  int id = blockIdx.x*256 + threadIdx.x;
  int px = id & 31, py = (id>>5)&31, ox = (id>>10)&31, oy = (id>>15)&31, b = id>>20;
  int y0,y1,x0,x1,u0,u1,v0,v1; float fy,fx,fu,fv;
  cw_coord(oy,16,32,y0,y1,fy); cw_coord(ox,16,32,x0,x1,fx);
  cw_coord(py,16,32,u0,u1,fu); cw_coord(px,16,32,v0,v1,fv);
  const float* in = ws + OFF_MAXED + (size_t)b*65536;
  int ys[2]={y0,y1}, xs[2]={x0,x1}, us[2]={u0,u1}, vs[2]={v0,v1};
  float wy[2]={1.f-fy,fy}, wx[2]={1.f-fx,fx}, wu[2]={1.f-fu,fu}, wv[2]={1.f-fv,fv};
  float s = 0.f;
  #pragma unroll
  for (int ia=0; ia<2; ia++)
    #pragma unroll
    for (int ic=0; ic<2; ic++){
      float wyx = wy[ia]*wx[ic];
      const float* base = in + ((size_t)ys[ia]*16 + xs[ic])*256;
      #pragma unroll
      for (int id_=0; id_<2; id_++)
        #pragma unroll
        for (int ie=0; ie<2; ie++)
          s += wyx*wu[id_]*wv[ie]*base[(size_t)us[id_]*16 + vs[ie]];
    }
  ws[OFF_INT32 + id] = s;
}

// ---------------------------------------------------------------------------
// 9) fast4d v3 (R7): 4 sx-outputs/block, dbuf plane staging, reg prefetch
__global__ __launch_bounds__(256) void k_fast4d(float* __restrict__ ws,
                                                const float* __restrict__ k4,
                                                const float* __restrict__ b4,
                                                float* __restrict__ out){
  const int b = blockIdx.y;
  const int sy = blockIdx.x >> 3, sx0 = (blockIdx.x & 7) << 2;
  const int t = threadIdx.x;
  const int y = t >> 3, x0 = (t & 7) << 2;
  __shared__ __align__(16) float sQ[2][36*48];
  for (int i=t; i<1728; i+=256){ sQ[0][i]=0.f; sQ[1][i]=0.f; }
  __syncthreads();
  const float* in = ws + OFF_INT32 + (size_t)b*1048576;
  float acc[4][4] = {};

  int i0 = 0;
  for (; i0 < 40; ++i0){
    int Y = sy + (i0>>3) - 2, X = sx0 - 2 + (i0&7);
    if (Y>=0 && Y<=31 && X>=0 && X<=31) break;
  }
  float4 pf = make_float4(0.f,0.f,0.f,0.f);
  if (i0 < 40){
    int Y = sy + (i0>>3) - 2, X = sx0 - 2 + (i0&7);
    pf = *reinterpret_cast<const float4*>(in + (size_t)(Y*32+X)*1024 + t*4);
  }
  int cur = 0, i = i0;
  const int srow = t >> 3, scol4 = (t & 7) << 2;
  #pragma unroll 1
  while (i < 40){
    int nx = i+1;
    for (; nx < 40; ++nx){
      int Y = sy + (nx>>3) - 2, X = sx0 - 2 + (nx&7);
      if (Y>=0 && Y<=31 && X>=0 && X<=31) break;
    }
    float* wp = &sQ[cur][(2+srow)*48 + 2 + scol4];
    wp[0]=pf.x; wp[1]=pf.y; wp[2]=pf.z; wp[3]=pf.w;
    if (nx < 40){
      int Y = sy + (nx>>3) - 2, X = sx0 - 2 + (nx&7);
      pf = *reinterpret_cast<const float4*>(in + (size_t)(Y*32+X)*1024 + t*4);
    }
    __syncthreads();
    const int a = i>>3, Xi = i&7;
    const float* ka = k4 + a*125;
    #pragma unroll
    for (int d=0; d<5; d++){
      const float* row = &sQ[cur][(y+d)*48 + x0];
      float4 q0 = *reinterpret_cast<const float4*>(row);
      float4 q1 = *reinterpret_cast<const float4*>(row+4);
      float r8[8] = {q0.x,q0.y,q0.z,q0.w,q1.x,q1.y,q1.z,q1.w};
      #pragma unroll
      for (int j=0; j<4; j++){
        const int c = Xi - j;
        if (c >= 0 && c <= 4){
          const float* kc = ka + c*25 + d*5;
          #pragma unroll
          for (int e=0; e<5; e++){
            float wv = kc[e];
            #pragma unroll
            for (int xi=0; xi<4; xi++)
              acc[j][xi] = fmaf(r8[xi+e], wv, acc[j][xi]);
          }
        }
      }
    }
    cur ^= 1; i = nx;
  }
  float bias = b4[0];
  #pragma unroll
  for (int j=0; j<4; j++){
    float4 o;
    float* po = &o.x;
    #pragma unroll
    for (int xi=0; xi<4; xi++){
      float xv = acc[j][xi] + bias;
      po[xi] = fmaxf(xv,0.f) + log1pf(expf(-fabsf(xv)));
    }
    *reinterpret_cast<float4*>(
      out + ((size_t)b*1024 + sy*32 + sx0 + j)*1024 + y*32 + x0) = o;
  }
}

// ---------------------------------------------------------------------------
// 10-12) mutual_nn_filter
__global__ void k_rowmax(const float* __restrict__ cm, float* __restrict__ ws){
  int row = blockIdx.x;
  const float* r = cm + (size_t)row*1024;
  int t = threadIdx.x;
  float m = -1e30f;
  for (int i=t; i<1024; i+=256) m = fmaxf(m, r[i]);
  __shared__ float red[256];
  red[t] = m; __syncthreads();
  for (int off=128; off; off>>=1){
    if (t < off) red[t] = fmaxf(red[t], red[t+off]);
    __syncthreads();
  }
  if (!t) ws[OFF_SMAX + row] = red[0];
}

__global__ void k_colmax_p(const float* __restrict__ cm, float* __restrict__ ws){
  int b = blockIdx.x >> 5, rg = (blockIdx.x >> 2) & 7, cg = blockIdx.x & 3;
  int c = cg*256 + threadIdx.x;
  const float* base = cm + (size_t)b*1048576 + (size_t)rg*131072 + c;
  float m = -1e30f;
  #pragma unroll 4
  for (int r=0; r<128; r++) m = fmaxf(m, base[(size_t)r*1024]);
  ws[OFF_CMAXP + (size_t)(b*8+rg)*1024 + c] = m;
}

__global__ void k_colmax_r(float* __restrict__ ws){
  int id = blockIdx.x*256 + threadIdx.x;         // 4096
  int b = id >> 10, c = id & 1023;
  float m = -1e30f;
  #pragma unroll
  for (int rg=0; rg<8; rg++)
    m = fmaxf(m, ws[OFF_CMAXP + (size_t)(b*8+rg)*1024 + c]);
  ws[OFF_TMAX + id] = m;
}

__global__ void k_mutual(float* __restrict__ cm, const float* __restrict__ ws){
  int id = blockIdx.x*256 + threadIdx.x;
  int b = id >> 20, r = (id>>10)&1023, c = id&1023;
  float v  = cm[id];
  float sm = ws[OFF_SMAX + (b<<10) + r];
  float tm = ws[OFF_TMAX + (b<<10) + c];
  sm = (sm==0.f) ? 1e-30f : sm;
  tm = (tm==0.f) ? 1e-30f : tm;
  cm[id] = v * (v/sm) * (v/tm);
}

// ---------------------------------------------------------------------------
extern "C" void kernel_launch(void* const* d_in, const int* in_sizes, int n_in,
                              void* d_out, int out_size, void* d_ws, size_t ws_size,
                              hipStream_t stream){
  const float* src = (const float*)d_in[0];
  const float* trg = (const float*)d_in[1];
  const float* w0  = (const float*)d_in[2];
  const float* w1  = (const float*)d_in[3];
  const float* w2  = (const float*)d_in[4];
  const float* k6  = (const float*)d_in[5];
  const float* k4  = (const float*)d_in[6];
  const float* b4  = (const float*)d_in[7];
  float* ws  = (float*)d_ws;    // needs WS_FLOATS*4 = ~72.1 MB
  float* out = (float*)d_out;
  (void)in_sizes; (void)n_in; (void)out_size; (void)ws_size;

  k_wpack       <<<3456,  256, 0, stream>>>(w0, w1, w2, ws);
  k_wa          <<<94,    256, 0, stream>>>(k6, ws);
  k_inpack      <<<512,   256, 0, stream>>>(src, trg, ws);
  k_conv_mfma   <<<672,   256, 0, stream>>>(ws);
  k_combine     <<<10752, 256, 0, stream>>>(ws);
  k_invnorm     <<<42,    256, 0, stream>>>(ws);
  k_corr        <<<1764,  256, 0, stream>>>(ws);
  k_interp_pairs<<<9216,  256, 0, stream>>>(ws);
  k_cl          <<<40320, 256, 0, stream>>>(ws);
  k_chm6d       <<<1024,  256, 0, stream>>>(ws);
  k_interp32    <<<16384, 256, 0, stream>>>(ws);
  k_fast4d      <<<dim3(256,4),  256, 0, stream>>>(ws, k4, b4, out);
  k_rowmax      <<<4096,  256, 0, stream>>>(out, ws);
  k_colmax_p    <<<128,   256, 0, stream>>>(out, ws);
  k_colmax_r    <<<16,    256, 0, stream>>>(ws);
  k_mutual      <<<16384, 256, 0, stream>>>(out, ws);
}

// Round 13
// 466.059 us; speedup vs baseline: 1.3074x; 1.0134x over previous
//
#include <hip/hip_runtime.h>
#include <cstdint>
#include <cstddef>

// ============================================================================
// CHMLearner forward. R13: fast4d v4 (fully aligned conflict-free LDS: interior
// at col 4, one b128 write, three b128 reads w/ r12 window); wpack v2
// (LDS-transposed coalesced weight pack). Rest identical to R12.
// ============================================================================

#define DEVFN __device__ __forceinline__

typedef __attribute__((ext_vector_type(8))) short short8v;
typedef __attribute__((ext_vector_type(4))) float f32x4;
typedef unsigned int u32;

DEVFN void gl_lds16(const void* g, void* l){
  __builtin_amdgcn_global_load_lds(
      (const __attribute__((address_space(1))) u32*)g,
      (__attribute__((address_space(3))) u32*)l, 16, 0, 0);
}

// workspace layout (float units). Total ~72.1 MB
constexpr size_t OFF_WB    = 0;           // bf16 packed conv weights
constexpr size_t OFF_P8    = 3538944;     // bf16 padded ch-last features
constexpr size_t OFF_P16   = 3948544;
constexpr size_t OFF_P32   = 5275648;
constexpr size_t OFF_SF8   = 10010624;    // conv outputs f32 [b][256][S*S]
constexpr size_t OFF_TF8   = 10076160;
constexpr size_t OFF_SF16  = 10141696;
constexpr size_t OFF_TF16  = 10403840;
constexpr size_t OFF_SF32  = 10665984;
constexpr size_t OFF_TF32  = 11714560;
constexpr size_t OFF_INVS  = 12763136;
constexpr size_t OFF_INVT  = 12768512;
constexpr size_t OFF_SMAX  = 12773888;
constexpr size_t OFF_TMAX  = 12777984;
constexpr size_t OFF_CORR6 = 12782080;    // [4][9][16^4] f32
constexpr size_t OFF_CMAXP = OFF_CORR6 + 2359296 + 128;   // 32768 colmax partials
constexpr size_t OFF_WA    = OFF_CMAXP + 32768;           // 192,000 bf16
constexpr size_t OFF_PARTK = OFF_WA + 96128;              // 2,752,512 conv K-partials
constexpr size_t WS_FLOATS = OFF_PARTK + 2752512;

// aliases into dead regions (all of [0, 10,010,624) is dead post-corr):
__device__ constexpr size_t PAIR_OFF[9] = {   // raw per-pair corr [4][ss^2][ts^2]
  OFF_WB + 0,       OFF_WB + 16384,   OFF_WB + 81920,
  OFF_WB + 344064,  OFF_WB + 409600,  OFF_WB + 671744,
  OFF_WB + 1720320, OFF_WB + 1982464, OFF_WB + 3031040 };
constexpr size_t OFF_CL    = 0;            // bf16 [4][256][20][21][24]
constexpr size_t OFF_MAXED = 9437184;      // [4][16^4] f32
constexpr size_t OFF_INT32 = 262144;       // [4][32^4] f32 (CL dead by interp32)

__device__ constexpr int SSARR[3] = {8, 16, 32};
__device__ constexpr int PAIR_START[9] = {0,4,20,84,100,164,420,484,740}; // 1764

DEVFN unsigned short f2bf(float f){
  unsigned int u = __float_as_uint(f);
  return (unsigned short)((u + 0x7fffu + ((u >> 16) & 1u)) >> 16);
}

// ---------------------------------------------------------------------------
// 1) wpack v2: coalesced via LDS transpose. 768 blocks = scale*16cg*16ig.
//    Load 16co x 64ci x 9tap slab (contiguous per co), emit MFMA A-fragments.
__global__ __launch_bounds__(256) void k_wpack(const float* __restrict__ w0,
                                               const float* __restrict__ w1,
                                               const float* __restrict__ w2,
                                               float* __restrict__ wsf){
  int bx = blockIdx.x;
  int scale = bx >> 8, cg = (bx >> 4) & 15, ig = bx & 15;
  const float* w = (scale==0) ? w0 : (scale==1 ? w1 : w2);
  const int t = threadIdx.x;
  __shared__ float sW[16*580];                   // [co][ci*9+tap], row pad 576->580
  const float* src = w + (size_t)cg*16*9216 + (size_t)ig*576;
  for (int i=t; i<9216; i+=256){
    int co = i/576, r = i%576;
    sW[co*580 + r] = src[(size_t)co*9216 + r];
  }
  __syncthreads();
  unsigned short* ob = (unsigned short*)(wsf + OFF_WB) + (size_t)scale*2359296;
  for (int f=t; f<1152; f+=256){                 // 9 tap x 2 kcl x 64 lanes
    int tap = f/128, rem = f%128, kcl = rem>>6, l = rem&63;
    int kc = ig*2 + kcl;
    int co = l & 15;
    int ciL = kcl*32 + ((l>>4)&3)*8;
    unsigned short* o = ob + ((size_t)tap*32768 + (size_t)kc*1024 + (size_t)cg*64 + l)*8;
    #pragma unroll
    for (int i=0;i<8;i++)
      o[i] = f2bf(sW[co*580 + (ciL+i)*9 + tap]);
  }
}

// 1b) pack chm6d weights into MFMA A-fragment order
__global__ void k_wa(const float* __restrict__ k6, float* __restrict__ wsf){
  int gid = blockIdx.x*256 + threadIdx.x;        // 24,000
  if (gid >= 24000) return;
  int tap = gid / 192, rem = gid % 192;
  int kc = rem / 64, l = rem % 64;
  int d = tap % 5, ac = tap / 5, a = ac / 5, c = ac % 5;
  int so = l & 15, k8 = (l >> 4) * 8;
  unsigned short* o = (unsigned short*)(wsf + OFF_WA) + (size_t)gid*8;
  #pragma unroll
  for (int i=0;i<8;i++){
    int kg = kc*32 + k8 + i;
    int e = kg >> 4, pr = kg & 15;
    float v = 0.f;
    if (so < 9 && pr < 9 && e < 5){
      int pi = pr/3, pj = pr%3, sio = so/3, sjo = so%3;
      int ki = pi - sio + 1, kj = pj - sjo + 1;
      if (ki>=0 && ki<=2 && kj>=0 && kj<=2)
        v = k6[(((((ki*3+kj)*5 + a)*5 + c)*5 + d)*5) + e];
    }
    o[i] = f2bf(v);
  }
}

// ---------------------------------------------------------------------------
// 2) inpack: stage 16 channels' 16x16 planes in LDS; emit all 3 scales
__global__ __launch_bounds__(256) void k_inpack(const float* __restrict__ src,
                                                const float* __restrict__ trg,
                                                float* __restrict__ wsf){
  int bt = blockIdx.x >> 6, cg = blockIdx.x & 63;
  int chbase = cg*16;
  int t = threadIdx.x;
  __shared__ float sIn[16][257];
  const float* gin = ((bt>=4)? trg : src) + ((size_t)(bt&3)*1024 + chbase)*256;
  #pragma unroll
  for (int i=0;i<16;i++){
    int idx = t + i*256; int ch = idx>>8, pos = idx&255;
    sIn[ch][pos] = gin[(size_t)ch*256 + pos];
  }
  __syncthreads();
  int ch = t & 15, pw = t >> 4;
  #pragma unroll 1
  for (int s=0; s<3; s++){
    int S = SSARR[s], Sp = S+2, Sp2 = Sp*Sp;
    size_t poff = (s==0)?OFF_P8 : (s==1)?OFF_P16 : OFF_P32;
    unsigned short* o = (unsigned short*)(wsf + poff) + (size_t)bt*Sp2*1024 + chbase + ch;
    float rs = 15.f/(float)(S-1);
    for (int i = pw; i < Sp2; i += 16){
      int py = i / Sp, px = i % Sp;
      float v = 0.f;
      if (py>0 && py<Sp-1 && px>0 && px<Sp-1){
        float cy = (float)(py-1)*rs, cx = (float)(px-1)*rs;
        int y0 = (int)cy; if (y0>15) y0=15; int y1 = (y0+1<16)?y0+1:15; float fy = cy-(float)y0;
        int x0 = (int)cx; if (x0>15) x0=15; int x1 = (x0+1<16)?x0+1:15; float fx = cx-(float)x0;
        v = (1.f-fy)*((1.f-fx)*sIn[ch][y0*16+x0] + fx*sIn[ch][y0*16+x1])
          +       fy*((1.f-fx)*sIn[ch][y1*16+x0] + fx*sIn[ch][y1*16+x1]);
      }
      o[(size_t)i*1024] = f2bf(v);
    }
  }
}

// ---------------------------------------------------------------------------
// 3) conv3x3 bf16 MFMA GEMM, K-split x2 (R12)
__global__ __launch_bounds__(256) void k_conv_mfma(float* __restrict__ wsf){
  int bs = (blockIdx.x & 7)*84 + (blockIdx.x >> 3);   // bijective, 672 blocks
  const int ks = bs & 1;
  int bx = bs >> 1;
  int scale, bt, cot, post, S, lgS;
  if (bx < 256)      { scale=2; S=32; lgS=5; bt=bx>>5; cot=(bx>>4)&1; post=bx&15; }
  else if (bx < 320) { int r=bx-256; scale=1; S=16; lgS=4; bt=r>>3; cot=(r>>2)&1; post=r&3; }
  else               { int r=bx-320; scale=0; S=8;  lgS=3; bt=r>>1; cot=r&1; post=0; }
  const int Sp = S+2, N = S*S;
  const unsigned short* WbS = (const unsigned short*)(wsf + OFF_WB) + (size_t)scale*2359296;
  size_t poff = scale==0?OFF_P8: scale==1?OFF_P16:OFF_P32;
  const unsigned short* Pb = (const unsigned short*)(wsf + poff) + (size_t)bt*Sp*Sp*1024;
  size_t obase = (scale==2) ? (bt>=4?OFF_TF32:OFF_SF32)
               : (scale==1) ? (bt>=4?OFF_TF16:OFF_SF16)
                            : (bt>=4?OFF_TF8 :OFF_SF8);
  if (ks) obase += OFF_PARTK - OFF_SF8;
  float* outp = wsf + obase + (size_t)(bt&3)*256*N;

  const int t = threadIdx.x, l = t&63, w = t>>6, wm = w&1, wn = w>>1;
  const int nc_base = cot*8;
  const int pos0 = post*64;
  const int it0 = ks*72, it1 = it0 + 72;

  __shared__ __align__(16) unsigned short Ab[2][8192];   // 32 KB
  __shared__ __align__(16) unsigned short Bb[2][4096];   // 16 KB

  f32x4 acc[4][2];
  #pragma unroll
  for (int i=0;i<4;i++)
    #pragma unroll
    for (int j=0;j<2;j++) acc[i][j] = (f32x4){0.f,0.f,0.f,0.f};

  auto STAGE = [&](int buf, int it){
    int tap = it>>4, kq = it&15;
    int dy = tap/3, dx = tap - dy*3;
    #pragma unroll
    for (int j=0;j<4;++j){
      int c = w + j*4;
      int kc = c>>3, nc = c&7;
      const unsigned short* src =
        WbS + ((((size_t)tap*32 + kq*2 + kc)*16 + nc_base + nc)*64 + l)*8;
      gl_lds16(src, &Ab[buf][c*512]);
    }
    #pragma unroll
    for (int j=0;j<2;++j){
      int c = w + j*4;
      int kc = c>>2, np = c&3;
      int pos = pos0 + np*16 + (l&15);
      int y = pos>>lgS, x = pos&(S-1);
      int row = (y+dy)*Sp + (x+dx);
      int ci = kq*64 + kc*32 + ((l>>4)<<3);
      gl_lds16(Pb + (size_t)row*1024 + ci, &Bb[buf][c*512]);
    }
  };

  STAGE(0, it0);
  __syncthreads();
  int buf = 0;
  #pragma unroll 1
  for (int it=it0; it<it1; ++it){
    if (it+1 < it1) STAGE(buf^1, it+1);
    #pragma unroll
    for (int kc=0; kc<2; ++kc){
      short8v a0 = *(const short8v*)&Ab[buf][((kc*8 + wm*4 + 0)*64 + l)*8];
      short8v a1 = *(const short8v*)&Ab[buf][((kc*8 + wm*4 + 1)*64 + l)*8];
      short8v a2 = *(const short8v*)&Ab[buf][((kc*8 + wm*4 + 2)*64 + l)*8];
      short8v a3 = *(const short8v*)&Ab[buf][((kc*8 + wm*4 + 3)*64 + l)*8];
      short8v b0 = *(const short8v*)&Bb[buf][((kc*4 + wn*2 + 0)*64 + l)*8];
      short8v b1 = *(const short8v*)&Bb[buf][((kc*4 + wn*2 + 1)*64 + l)*8];
      acc[0][0] = __builtin_amdgcn_mfma_f32_16x16x32_bf16(a0, b0, acc[0][0], 0,0,0);
      acc[1][0] = __builtin_amdgcn_mfma_f32_16x16x32_bf16(a1, b0, acc[1][0], 0,0,0);
      acc[2][0] = __builtin_amdgcn_mfma_f32_16x16x32_bf16(a2, b0, acc[2][0], 0,0,0);
      acc[3][0] = __builtin_amdgcn_mfma_f32_16x16x32_bf16(a3, b0, acc[3][0], 0,0,0);
      acc[0][1] = __builtin_amdgcn_mfma_f32_16x16x32_bf16(a0, b1, acc[0][1], 0,0,0);
      acc[1][1] = __builtin_amdgcn_mfma_f32_16x16x32_bf16(a1, b1, acc[1][1], 0,0,0);
      acc[2][1] = __builtin_amdgcn_mfma_f32_16x16x32_bf16(a2, b1, acc[2][1], 0,0,0);
      acc[3][1] = __builtin_amdgcn_mfma_f32_16x16x32_bf16(a3, b1, acc[3][1], 0,0,0);
    }
    __syncthreads();
    buf ^= 1;
  }

  const int r0 = (l>>4)*4, cl = l&15;
  float* ob = outp + (size_t)(cot*128 + wm*64)*N + pos0 + wn*32 + cl;
  #pragma unroll
  for (int mf=0; mf<4; ++mf)
    #pragma unroll
    for (int nf=0; nf<2; ++nf){
      float* op = ob + (size_t)(mf*16 + r0)*N + nf*16;
      #pragma unroll
      for (int i=0;i<4;++i) op[(size_t)i*N] = acc[mf][nf][i];
    }
}

// 3b) combine conv K-partials: outputs += PARTK
__global__ void k_combine(float* __restrict__ ws){
  int i = blockIdx.x*256 + threadIdx.x;          // 2,752,512 exact
  ws[OFF_SF8 + i] += ws[OFF_PARTK + i];
}

// ---------------------------------------------------------------------------
// 4) inverse feature norms per position
__global__ void k_invnorm(float* __restrict__ ws){
  int id = blockIdx.x*256 + threadIdx.x;
  if (id >= 10752) return;
  int tsr = id / 5376, r = id % 5376;
  int P, q; size_t fbase;
  if (r < 256)     { P=64;   q=r;      fbase = tsr ? OFF_TF8  : OFF_SF8; }
  else if (r<1280) { P=256;  q=r-256;  fbase = tsr ? OFF_TF16 : OFF_SF16; }
  else             { P=1024; q=r-1280; fbase = tsr ? OFF_TF32 : OFF_SF32; }
  int b = q / P, pos = q % P;
  const float* f = ws + fbase + (size_t)b*256*P + pos;
  float s = 0.f;
  for (int ch=0; ch<256; ch++){ float v = f[(size_t)ch*P]; s = fmaf(v,v,s); }
  ws[(tsr ? OFF_INVT : OFF_INVS) + r] = 1.f/sqrtf(s);
}

// ---------------------------------------------------------------------------
// 5) all 9 normalized-correlation GEMMs (f32), 64x64 tiles, K=256
__global__ __launch_bounds__(256) void k_corr(float* __restrict__ ws){
  int bx = blockIdx.x;
  int p = (bx>=4)+(bx>=20)+(bx>=84)+(bx>=100)+(bx>=164)+(bx>=420)+(bx>=484)+(bx>=740);
  int si = p/3, ti = p%3;
  int M = SSARR[si]*SSARR[si], N = SSARR[ti]*SSARR[ti];
  int ntN = N >> 6;
  int rem = bx - PAIR_START[p];
  int b = rem & 3; rem >>= 2;
  int nt = rem % ntN, mt = rem / ntN;
  int m0 = mt*64, n0 = nt*64;
  const float* A  = ws + (si==0?OFF_SF8: si==1?OFF_SF16:OFF_SF32) + (size_t)b*256*M;
  const float* Bp = ws + (ti==0?OFF_TF8: ti==1?OFF_TF16:OFF_TF32) + (size_t)b*256*N;
  const float* iS = ws + OFF_INVS + (si==0?0: si==1?256:1280) + (size_t)b*M;
  const float* iT = ws + OFF_INVT + (ti==0?0: ti==1?256:1280) + (size_t)b*N;
  float* C = ws + PAIR_OFF[p] + (size_t)b*M*N;
  __shared__ __align__(16) float As[16][64];
  __shared__ __align__(16) float Bs[16][64];
  int t = threadIdx.x, tm = t>>4, tn = t&15;
  float acc[4][4] = {};
  #pragma unroll 1
  for (int k0=0; k0<256; k0+=16){
    __syncthreads();
    #pragma unroll
    for (int i=0;i<4;i++){
      int idx = t + i*256; int k = idx>>6, m = idx&63;
      As[k][m] = A [(size_t)(k0+k)*M + m0+m];
      Bs[k][m] = Bp[(size_t)(k0+k)*N + n0+m];
    }
    __syncthreads();
    #pragma unroll
    for (int k=0;k<16;k++){
      float4 av = *reinterpret_cast<const float4*>(&As[k][tm*4]);
      float4 bv = *reinterpret_cast<const float4*>(&Bs[k][tn*4]);
      float a4[4]={av.x,av.y,av.z,av.w}, b4[4]={bv.x,bv.y,bv.z,bv.w};
      #pragma unroll
      for (int i=0;i<4;i++)
        #pragma unroll
        for (int j=0;j<4;j++)
          acc[i][j] = fmaf(a4[i], b4[j], acc[i][j]);
    }
  }
  #pragma unroll
  for (int i=0;i<4;i++){
    float sv = iS[m0+tm*4+i];
    #pragma unroll
    for (int j=0;j<4;j++)
      C[(size_t)(m0+tm*4+i)*N + n0+tn*4+j] = acc[i][j]*sv*iT[n0+tn*4+j];
  }
}

// ---------------------------------------------------------------------------
DEVFN void cw_coord(int i, int n, int OH, int& i0, int& i1, float& f){
  float c = (float)(i*(n-1))/(float)(OH-1);
  int a = (int)c; if (a > n-1) a = n-1;
  i0 = a; i1 = (a+1 < n) ? a+1 : n-1; f = c - (float)a;
}

// 6) interp_pairs v2: block = (p,b,oy,ox); stage 4 corner (y,x) planes in LDS
__global__ __launch_bounds__(256) void k_interp_pairs(float* __restrict__ ws){
  int bx = blockIdx.x;
  int p = bx >> 10;
  int bl = bx & 1023;                    // [b:2][oy:4][ox:4]
  int b = bl >> 8, oy = (bl >> 4) & 15, ox = bl & 15;
  int si = p/3, ti = p%3;
  int h1 = SSARR[si], t1 = SSARR[ti], t12 = t1*t1;
  int y0,y1,x0,x1; float fy,fx;
  cw_coord(oy,h1,16,y0,y1,fy); cw_coord(ox,h1,16,x0,x1,fx);
  const float* in = ws + PAIR_OFF[p] + (size_t)b*h1*h1*t12;
  __shared__ float sPl[4][1024];
  const int t = threadIdx.x;
  {
    const float* pl0 = in + (size_t)(y0*h1+x0)*t12;
    const float* pl1 = in + (size_t)(y0*h1+x1)*t12;
    const float* pl2 = in + (size_t)(y1*h1+x0)*t12;
    const float* pl3 = in + (size_t)(y1*h1+x1)*t12;
    for (int i=t; i<t12; i+=256){
      sPl[0][i] = pl0[i]; sPl[1][i] = pl1[i];
      sPl[2][i] = pl2[i]; sPl[3][i] = pl3[i];
    }
  }
  __syncthreads();
  int px = t & 15, py = t >> 4;
  int u0,u1,v0,v1; float fu,fv;
  cw_coord(py,t1,16,u0,u1,fu); cw_coord(px,t1,16,v0,v1,fv);
  float wY[2]={1.f-fy,fy}, wX[2]={1.f-fx,fx};
  float wU[2]={1.f-fu,fu}, wV[2]={1.f-fv,fv};
  int us[2]={u0,u1}, vs[2]={v0,v1};
  float s = 0.f;
  #pragma unroll
  for (int qa=0; qa<2; qa++)
    #pragma unroll
    for (int qc=0; qc<2; qc++){
      float wyx = wY[qa]*wX[qc];
      const float* base = sPl[qa*2+qc];
      #pragma unroll
      for (int qu=0; qu<2; qu++)
        #pragma unroll
        for (int qv=0; qv<2; qv++)
          s += wyx*wU[qu]*wV[qv]*base[us[qu]*t1 + vs[qv]];
    }
  ws[OFF_CORR6 + ((size_t)b*9 + p)*65536 + ((size_t)(oy*16+ox)<<8) + t] = fmaxf(s, 0.f);
}

// ---------------------------------------------------------------------------
// 6b) channels-last bf16 zero-padded copy for chm6d MFMA
__global__ void k_cl(float* __restrict__ ws){
  int g = blockIdx.x*256 + threadIdx.x;          // 10,321,920 exact
  int pr = g % 24; int q = g / 24;
  int xp = q % 21; q /= 21;
  int yp = q % 20; q /= 20;
  int yx = q & 255; int b = q >> 8;
  float v = 0.f;
  if (pr < 9 && yp >= 2 && yp < 18 && xp >= 2 && xp < 18)
    v = ws[OFF_CORR6 + (((size_t)b*9 + pr) << 16) + (size_t)yx*256 + (yp-2)*16 + (xp-2)];
  ((unsigned short*)(ws + OFF_CL))[g] = f2bf(v);
}

// ---------------------------------------------------------------------------
// 7) chm6d v7: bf16 MFMA implicit GEMM + fused sigmoid/max epilogue
__global__ __launch_bounds__(256) void k_chm6d(float* __restrict__ ws){
  int id = (blockIdx.x & 7)*128 + (blockIdx.x >> 3);   // XCD swizzle, bijective
  const int b = id >> 8, sy = (id >> 4) & 15, sx = id & 15;
  const int t = threadIdx.x, l = t & 63, w = t >> 6;
  const int x = l & 15, h = (l >> 4) & 1, e2 = (l >> 4) >> 1;
  const unsigned short* CLu = (const unsigned short*)(ws + OFF_CL);
  const unsigned short* WAu = (const unsigned short*)(ws + OFF_WA);
  __shared__ __align__(16) unsigned short tile[2][10080];   // 40,320 B

  f32x4 acc[4];
  #pragma unroll
  for (int i=0;i<4;i++) acc[i] = (f32x4){0.f,0.f,0.f,0.f};

  auto STAGE = [&](int buf, int YX){
    const unsigned short* src = CLu + (size_t)(b*256 + YX)*10080;
    #pragma unroll
    for (int j=0;j<5;++j){
      int ch = t + j*256;
      if (ch < 1260) gl_lds16(src + (size_t)ch*8, &tile[buf][ch*8]);
    }
  };

  const int xb0 = (x + e2)*24 + 8*h;

  int i0 = 0;
  for (; i0 < 25; ++i0){
    int Y = sy + i0/5 - 2, X = sx + i0%5 - 2;
    if (Y>=0 && Y<=15 && X>=0 && X<=15) break;
  }
  {
    int Y = sy + i0/5 - 2, X = sx + i0%5 - 2;
    STAGE(0, Y*16 + X);
  }
  __syncthreads();
  int buf = 0, i = i0;
  #pragma unroll 1
  while (i < 25){
    int nx = i + 1;
    for (; nx < 25; ++nx){
      int Y = sy + nx/5 - 2, X = sx + nx%5 - 2;
      if (Y>=0 && Y<=15 && X>=0 && X<=15) break;
    }
    if (nx < 25){
      int Y = sy + nx/5 - 2, X = sx + nx%5 - 2;
      STAGE(buf^1, Y*16 + X);
    }
    {
      const unsigned short* wa = WAu + (size_t)i*5*3*512;   // [d][kc][lane][8]
      short8v afr[5][3];
      #pragma unroll
      for (int d=0; d<5; ++d)
        #pragma unroll
        for (int kc=0; kc<3; ++kc)
          afr[d][kc] = *(const short8v*)&wa[((d*3 + kc)*64 + l)*8];
      const unsigned short* tb = &tile[buf][0];
      #pragma unroll
      for (int rl=0; rl<8; ++rl){
        const int row = (w*4 + rl)*504;
        short8v bf0 = *(const short8v*)&tb[row + xb0];
        short8v bf1 = *(const short8v*)&tb[row + xb0 + 48];
        short8v bf2 = *(const short8v*)&tb[row + xb0 + 96];
        #pragma unroll
        for (int y=0; y<4; ++y){
          if (y <= rl && rl - y <= 4){
            const int d = rl - y;
            acc[y] = __builtin_amdgcn_mfma_f32_16x16x32_bf16(afr[d][0], bf0, acc[y], 0,0,0);
            acc[y] = __builtin_amdgcn_mfma_f32_16x16x32_bf16(afr[d][1], bf1, acc[y], 0,0,0);
            acc[y] = __builtin_amdgcn_mfma_f32_16x16x32_bf16(afr[d][2], bf2, acc[y], 0,0,0);
          }
        }
      }
    }
    __syncthreads();
    buf ^= 1; i = nx;
  }

  const int g = l >> 4;
  float* maxed = ws + OFF_MAXED + (size_t)b*65536 + (size_t)(sy*16+sx)*256;
  #pragma unroll
  for (int y=0; y<4; ++y){
    float lm;
    if (g < 2)      lm = fmaxf(fmaxf(acc[y][0], acc[y][1]), fmaxf(acc[y][2], acc[y][3]));
    else if (g==2)  lm = acc[y][0];
    else            lm = -1e30f;
    lm = fmaxf(lm, __shfl_xor(lm, 16));
    lm = fmaxf(lm, __shfl_xor(lm, 32));
    if (l < 16)
      maxed[(w*4 + y)*16 + x] = 1.f/(1.f + expf(-lm));
  }
}

// ---------------------------------------------------------------------------
// 8) interpolate4d 16^4 -> 32^4
__global__ void k_interp32(float* __restrict__ ws){
  int id = blockIdx.x*256 + threadIdx.x;
  int px = id & 31, py = (id>>5)&31, ox = (id>>10)&31, oy = (id>>15)&31, b = id>>20;
  int y0,y1,x0,x1,u0,u1,v0,v1; float fy,fx,fu,fv;
  cw_coord(oy,16,32,y0,y1,fy); cw_coord(ox,16,32,x0,x1,fx);
  cw_coord(py,16,32,u0,u1,fu); cw_coord(px,16,32,v0,v1,fv);
  const float* in = ws + OFF_MAXED + (size_t)b*65536;
  int ys[2]={y0,y1}, xs[2]={x0,x1}, us[2]={u0,u1}, vs[2]={v0,v1};
  float wy[2]={1.f-fy,fy}, wx[2]={1.f-fx,fx}, wu[2]={1.f-fu,fu}, wv[2]={1.f-fv,fv};
  float s = 0.f;
  #pragma unroll
  for (int ia=0; ia<2; ia++)
    #pragma unroll
    for (int ic=0; ic<2; ic++){
      float wyx = wy[ia]*wx[ic];
      const float* base = in + ((size_t)ys[ia]*16 + xs[ic])*256;
      #pragma unroll
      for (int id_=0; id_<2; id_++)
        #pragma unroll
        for (int ie=0; ie<2; ie++)
          s += wyx*wu[id_]*wv[ie]*base[(size_t)us[id_]*16 + vs[ie]];
    }
  ws[OFF_INT32 + id] = s;
}

// ---------------------------------------------------------------------------
// 9) fast4d v4: fully aligned conflict-free LDS. Interior at col 4, stride 48
//    (slot = (4*srow+c+1) mod 8 — each 8-lane group covers all 8 16B slots).
//    One aligned b128 write/plane; 3 aligned b128 reads/d (r12 window).
__global__ __launch_bounds__(256) void k_fast4d(float* __restrict__ ws,
                                                const float* __restrict__ k4,
                                                const float* __restrict__ b4,
                                                float* __restrict__ out){
  const int b = blockIdx.y;
  const int sy = blockIdx.x >> 3, sx0 = (blockIdx.x & 7) << 2;
  const int t = threadIdx.x;
  const int y = t >> 3, x0 = (t & 7) << 2;
  __shared__ __align__(16) float sQ[2][36*48];
  for (int i=t; i<1728; i+=256){ sQ[0][i]=0.f; sQ[1][i]=0.f; }
  __syncthreads();
  const float* in = ws + OFF_INT32 + (size_t)b*1048576;
  float acc[4][4] = {};

  int i0 = 0;
  for (; i0 < 40; ++i0){
    int Y = sy + (i0>>3) - 2, X = sx0 - 2 + (i0&7);
    if (Y>=0 && Y<=31 && X>=0 && X<=31) break;
  }
  float4 pf = make_float4(0.f,0.f,0.f,0.f);
  if (i0 < 40){
    int Y = sy + (i0>>3) - 2, X = sx0 - 2 + (i0&7);
    pf = *reinterpret_cast<const float4*>(in + (size_t)(Y*32+X)*1024 + t*4);
  }
  int cur = 0, i = i0;
  const int srow = t >> 3, scol4 = (t & 7) << 2;
  const int wo = (2+srow)*48 + 4 + scol4;          // aligned b128 write
  #pragma unroll 1
  while (i < 40){
    int nx = i+1;
    for (; nx < 40; ++nx){
      int Y = sy + (nx>>3) - 2, X = sx0 - 2 + (nx&7);
      if (Y>=0 && Y<=31 && X>=0 && X<=31) break;
    }
    *reinterpret_cast<f32x4*>(&sQ[cur][wo]) = (f32x4){pf.x,pf.y,pf.z,pf.w};
    if (nx < 40){
      int Y = sy + (nx>>3) - 2, X = sx0 - 2 + (nx&7);
      pf = *reinterpret_cast<const float4*>(in + (size_t)(Y*32+X)*1024 + t*4);
    }
    __syncthreads();
    const int a = i>>3, Xi = i&7;
    const float* ka = k4 + a*125;
    #pragma unroll
    for (int d=0; d<5; d++){
      const float* row = &sQ[cur][(y+d)*48 + x0];   // aligned, conflict-free
      float4 q0 = *reinterpret_cast<const float4*>(row);
      float4 q1 = *reinterpret_cast<const float4*>(row+4);
      float4 q2 = *reinterpret_cast<const float4*>(row+8);
      float r12[12] = {q0.x,q0.y,q0.z,q0.w, q1.x,q1.y,q1.z,q1.w,
                       q2.x,q2.y,q2.z,q2.w};
      #pragma unroll
      for (int j=0; j<4; j++){
        const int c = Xi - j;
        if (c >= 0 && c <= 4){                      // wave-uniform predicate
          const float* kc = ka + c*25 + d*5;
          #pragma unroll
          for (int e=0; e<5; e++){
            float wv = kc[e];
            #pragma unroll
            for (int xi=0; xi<4; xi++)
              acc[j][xi] = fmaf(r12[xi+e+2], wv, acc[j][xi]);
          }
        }
      }
    }
    cur ^= 1; i = nx;
  }
  float bias = b4[0];
  #pragma unroll
  for (int j=0; j<4; j++){
    float4 o;
    float* po = &o.x;
    #pragma unroll
    for (int xi=0; xi<4; xi++){
      float xv = acc[j][xi] + bias;
      po[xi] = fmaxf(xv,0.f) + log1pf(expf(-fabsf(xv)));
    }
    *reinterpret_cast<float4*>(
      out + ((size_t)b*1024 + sy*32 + sx0 + j)*1024 + y*32 + x0) = o;
  }
}

// ---------------------------------------------------------------------------
// 10-12) mutual_nn_filter
__global__ void k_rowmax(const float* __restrict__ cm, float* __restrict__ ws){
  int row = blockIdx.x;
  const float* r = cm + (size_t)row*1024;
  int t = threadIdx.x;
  float m = -1e30f;
  for (int i=t; i<1024; i+=256) m = fmaxf(m, r[i]);
  __shared__ float red[256];
  red[t] = m; __syncthreads();
  for (int off=128; off; off>>=1){
    if (t < off) red[t] = fmaxf(red[t], red[t+off]);
    __syncthreads();
  }
  if (!t) ws[OFF_SMAX + row] = red[0];
}

__global__ void k_colmax_p(const float* __restrict__ cm, float* __restrict__ ws){
  int b = blockIdx.x >> 5, rg = (blockIdx.x >> 2) & 7, cg = blockIdx.x & 3;
  int c = cg*256 + threadIdx.x;
  const float* base = cm + (size_t)b*1048576 + (size_t)rg*131072 + c;
  float m = -1e30f;
  #pragma unroll 4
  for (int r=0; r<128; r++) m = fmaxf(m, base[(size_t)r*1024]);
  ws[OFF_CMAXP + (size_t)(b*8+rg)*1024 + c] = m;
}

__global__ void k_colmax_r(float* __restrict__ ws){
  int id = blockIdx.x*256 + threadIdx.x;         // 4096
  int b = id >> 10, c = id & 1023;
  float m = -1e30f;
  #pragma unroll
  for (int rg=0; rg<8; rg++)
    m = fmaxf(m, ws[OFF_CMAXP + (size_t)(b*8+rg)*1024 + c]);
  ws[OFF_TMAX + id] = m;
}

__global__ void k_mutual(float* __restrict__ cm, const float* __restrict__ ws){
  int id = blockIdx.x*256 + threadIdx.x;
  int b = id >> 20, r = (id>>10)&1023, c = id&1023;
  float v  = cm[id];
  float sm = ws[OFF_SMAX + (b<<10) + r];
  float tm = ws[OFF_TMAX + (b<<10) + c];
  sm = (sm==0.f) ? 1e-30f : sm;
  tm = (tm==0.f) ? 1e-30f : tm;
  cm[id] = v * (v/sm) * (v/tm);
}

// ---------------------------------------------------------------------------
extern "C" void kernel_launch(void* const* d_in, const int* in_sizes, int n_in,
                              void* d_out, int out_size, void* d_ws, size_t ws_size,
                              hipStream_t stream){
  const float* src = (const float*)d_in[0];
  const float* trg = (const float*)d_in[1];
  const float* w0  = (const float*)d_in[2];
  const float* w1  = (const float*)d_in[3];
  const float* w2  = (const float*)d_in[4];
  const float* k6  = (const float*)d_in[5];
  const float* k4  = (const float*)d_in[6];
  const float* b4  = (const float*)d_in[7];
  float* ws  = (float*)d_ws;    // needs WS_FLOATS*4 = ~72.1 MB
  float* out = (float*)d_out;
  (void)in_sizes; (void)n_in; (void)out_size; (void)ws_size;

  k_wpack       <<<768,   256, 0, stream>>>(w0, w1, w2, ws);
  k_wa          <<<94,    256, 0, stream>>>(k6, ws);
  k_inpack      <<<512,   256, 0, stream>>>(src, trg, ws);
  k_conv_mfma   <<<672,   256, 0, stream>>>(ws);
  k_combine     <<<10752, 256, 0, stream>>>(ws);
  k_invnorm     <<<42,    256, 0, stream>>>(ws);
  k_corr        <<<1764,  256, 0, stream>>>(ws);
  k_interp_pairs<<<9216,  256, 0, stream>>>(ws);
  k_cl          <<<40320, 256, 0, stream>>>(ws);
  k_chm6d       <<<1024,  256, 0, stream>>>(ws);
  k_interp32    <<<16384, 256, 0, stream>>>(ws);
  k_fast4d      <<<dim3(256,4),  256, 0, stream>>>(ws, k4, b4, out);
  k_rowmax      <<<4096,  256, 0, stream>>>(out, ws);
  k_colmax_p    <<<128,   256, 0, stream>>>(out, ws);
  k_colmax_r    <<<16,    256, 0, stream>>>(ws);
  k_mutual      <<<16384, 256, 0, stream>>>(out, ws);
}